// Round 4
// baseline (557.311 us; speedup 1.0000x reference)
//
#include <hip/hip_runtime.h>
#include <math.h>
#include <stdint.h>

#define NLV 16
#define NDENSE 6
#define NHASH 10

typedef float evf2 __attribute__((ext_vector_type(2)));
typedef float evf4 __attribute__((ext_vector_type(4)));

struct Params {          // all 16 levels (fallback kernel)
  float scale[NLV];
  uint32_t res[NLV];
  uint32_t msize[NLV];
  uint32_t offset[NLV];
};

struct ParamsD {         // dense levels 0..5
  float scale[NDENSE];
  uint32_t res[NDENSE];
  uint32_t msize[NDENSE];
  uint32_t offset[NDENSE];
};

// ---------- per-hashed-level pass: tmp[p] = feat2(level) ----------
__global__ __launch_bounds__(256) void hash_level_kernel(
    const float* __restrict__ positions,
    const float* __restrict__ tbl,      // table already offset to this level
    float2* __restrict__ tmp,
    float scale, uint32_t mask, int n)
{
  int p = blockIdx.x * 256 + threadIdx.x;
  if (p >= n) return;

  float x = (positions[3*p+0] + 1.0f) * 0.5f;
  float y = (positions[3*p+1] + 1.0f) * 0.5f;
  float z = (positions[3*p+2] + 1.0f) * 0.5f;

  float px = x * scale + 0.5f;
  float py = y * scale + 0.5f;
  float pz = z * scale + 0.5f;
  float fx = floorf(px), fy = floorf(py), fz = floorf(pz);
  float tx = px - fx, ty = py - fy, tz = pz - fz;
  uint32_t gx = (uint32_t)fx, gy = (uint32_t)fy, gz = (uint32_t)fz;

  float wx[2] = {1.0f - tx, tx};
  float wy[2] = {1.0f - ty, ty};
  float wz[2] = {1.0f - tz, tz};

  float f0 = 0.0f, f1 = 0.0f;
  #pragma unroll
  for (int c = 0; c < 8; ++c) {
    uint32_t cx = gx + (c & 1u);
    uint32_t cy = gy + ((c >> 1) & 1u);
    uint32_t cz = gz + ((c >> 2) & 1u);
    uint32_t h = (cx ^ (cy * 2654435761u) ^ (cz * 805459861u)) & mask;
    float w = (wx[c & 1u] * wy[(c >> 1) & 1u]) * wz[(c >> 2) & 1u];
    const float2 t = *reinterpret_cast<const float2*>(tbl + 2u * h);
    f0 += w * t.x;
    f1 += w * t.y;
  }
  // nt store: don't let the tmp stream evict this level's 4 MB table from L2
  evf2 v; v.x = f0; v.y = f1;
  __builtin_nontemporal_store(v, reinterpret_cast<evf2*>(tmp + p));
}

// ---------- dense levels inline + pack everything ----------
__global__ __launch_bounds__(256) void dense_pack_kernel(
    const float* __restrict__ positions,
    const float* __restrict__ table,
    const float2* __restrict__ tmp,     // [NHASH][n] level-major
    float* __restrict__ out,
    ParamsD prm, int n)
{
  int p = blockIdx.x * 256 + threadIdx.x;
  if (p >= n) return;

  float x = (positions[3*p+0] + 1.0f) * 0.5f;
  float y = (positions[3*p+1] + 1.0f) * 0.5f;
  float z = (positions[3*p+2] + 1.0f) * 0.5f;

  float acc[2*NDENSE];

  #pragma unroll
  for (int l = 0; l < NDENSE; ++l) {
    const float s = prm.scale[l];
    const uint32_t res = prm.res[l];
    const uint32_t ms = prm.msize[l];
    const float* __restrict__ tbl = table + 2u * prm.offset[l];
    const uint32_t res2 = res * res;

    float px = x * s + 0.5f;
    float py = y * s + 0.5f;
    float pz = z * s + 0.5f;
    float fx = floorf(px), fy = floorf(py), fz = floorf(pz);
    float tx = px - fx, ty = py - fy, tz = pz - fz;
    uint32_t gx = (uint32_t)fx, gy = (uint32_t)fy, gz = (uint32_t)fz;

    float wxa = 1.0f - tx, wxb = tx;
    float wy_[2] = {1.0f - ty, ty};
    float wz_[2] = {1.0f - tz, tz};

    float f0 = 0.0f, f1 = 0.0f;
    // x-pair corners are adjacent dense indices (h, h+1): one float4 per pair.
    #pragma unroll
    for (int cyz = 0; cyz < 4; ++cyz) {
      uint32_t cy = gy + (cyz & 1u);
      uint32_t cz = gz + ((cyz >> 1) & 1u);
      uint32_t h = gx + cy * res + cz * res2;   // corner a; h < 2*ms always
      if (h >= ms) h -= ms;
      float wyz = wy_[cyz & 1u] * wz_[(cyz >> 1) & 1u];
      float2 ta, tb;
      if (h + 1u < ms) {                        // common: corner b = h+1
        const float4 t4 = *reinterpret_cast<const float4*>(tbl + 2u * h);
        ta.x = t4.x; ta.y = t4.y; tb.x = t4.z; tb.y = t4.w;
      } else {                                  // rare: corner b wraps to 0
        ta = *reinterpret_cast<const float2*>(tbl + 2u * h);
        tb = *reinterpret_cast<const float2*>(tbl);
      }
      // same corner order & weight-product shape as reference (c=0..7)
      float wa = wxa * wyz, wb = wxb * wyz;
      f0 += wa * ta.x; f1 += wa * ta.y;
      f0 += wb * tb.x; f1 += wb * tb.y;
    }
    acc[2*l]   = f0;
    acc[2*l+1] = f1;
  }

  // hashed-level temps: coalesced nt loads (streaming, keep L2 for tables)
  evf2 hv[NHASH];
  #pragma unroll
  for (int j = 0; j < NHASH; ++j)
    hv[j] = __builtin_nontemporal_load(
        reinterpret_cast<const evf2*>(tmp + (size_t)j * n + p));

  evf4 o0, o1, o2;
  o0.x = acc[0]; o0.y = acc[1]; o0.z = acc[2];  o0.w = acc[3];
  o1.x = acc[4]; o1.y = acc[5]; o1.z = acc[6];  o1.w = acc[7];
  o2.x = acc[8]; o2.y = acc[9]; o2.z = acc[10]; o2.w = acc[11];
  evf4* o = reinterpret_cast<evf4*>(out + (size_t)p * 32u);
  __builtin_nontemporal_store(o0, o + 0);
  __builtin_nontemporal_store(o1, o + 1);
  __builtin_nontemporal_store(o2, o + 2);
  #pragma unroll
  for (int j = 0; j < 5; ++j) {
    evf4 ov;
    ov.x = hv[2*j].x; ov.y = hv[2*j].y; ov.z = hv[2*j+1].x; ov.w = hv[2*j+1].y;
    __builtin_nontemporal_store(ov, o + 3 + j);
  }
}

// ---------- fallback: single fused kernel ----------
__global__ __launch_bounds__(256) void hash_enc_kernel(
    const float* __restrict__ positions,
    const float* __restrict__ table,
    float* __restrict__ out,
    Params prm, int n)
{
  int p = blockIdx.x * 256 + threadIdx.x;
  if (p >= n) return;

  float x = (positions[3*p+0] + 1.0f) * 0.5f;
  float y = (positions[3*p+1] + 1.0f) * 0.5f;
  float z = (positions[3*p+2] + 1.0f) * 0.5f;

  float acc[32];

  #pragma unroll
  for (int l = 0; l < NLV; ++l) {
    const float s = prm.scale[l];
    const uint32_t res = prm.res[l];
    const uint32_t ms = prm.msize[l];
    const uint32_t off = prm.offset[l];

    float px = x * s + 0.5f;
    float py = y * s + 0.5f;
    float pz = z * s + 0.5f;
    float fx = floorf(px), fy = floorf(py), fz = floorf(pz);
    float tx = px - fx, ty = py - fy, tz = pz - fz;
    uint32_t gx = (uint32_t)fx, gy = (uint32_t)fy, gz = (uint32_t)fz;

    float wx[2] = {1.0f - tx, tx};
    float wy[2] = {1.0f - ty, ty};
    float wz[2] = {1.0f - tz, tz};

    float f0 = 0.0f, f1 = 0.0f;
    #pragma unroll
    for (int c = 0; c < 8; ++c) {
      uint32_t cx = gx + (c & 1u);
      uint32_t cy = gy + ((c >> 1) & 1u);
      uint32_t cz = gz + ((c >> 2) & 1u);
      uint32_t h;
      if (l < NDENSE) {
        h = cx + cy * res + cz * res * res;
        if (h >= ms) h -= ms;
      } else {
        h = cx ^ (cy * 2654435761u) ^ (cz * 805459861u);
        h &= (ms - 1u);
      }
      float w = (wx[c & 1u] * wy[(c >> 1) & 1u]) * wz[(c >> 2) & 1u];
      const float2 t = *reinterpret_cast<const float2*>(table + 2u * (h + off));
      f0 += w * t.x;
      f1 += w * t.y;
    }
    acc[2*l]   = f0;
    acc[2*l+1] = f1;
  }

  float4* o = reinterpret_cast<float4*>(out + (size_t)p * 32u);
  #pragma unroll
  for (int k = 0; k < 8; ++k)
    o[k] = make_float4(acc[4*k+0], acc[4*k+1], acc[4*k+2], acc[4*k+3]);
}

extern "C" void kernel_launch(void* const* d_in, const int* in_sizes, int n_in,
                              void* d_out, int out_size, void* d_ws, size_t ws_size,
                              hipStream_t stream) {
  const float* positions = (const float*)d_in[0];
  const float* table     = (const float*)d_in[1];
  float* out             = (float*)d_out;
  int n = in_sizes[0] / 3;

  // Level metadata, exactly mirroring the reference (f64 exp/log; f32 cast
  // for the encode-path scale; level 5 is dense with res=65 due to the
  // B_SCALE^5 = 4.0000007 float quirk).
  Params prm;
  const double lnb = log(1.3195079565048218);
  uint32_t off = 0;
  for (int l = 0; l < NLV; ++l) {
    double sd = 16.0 * exp((double)l * lnb) - 1.0;
    uint32_t res_meta = (uint32_t)ceil(sd) + 1u;
    uint64_t p3 = (uint64_t)res_meta * res_meta * res_meta;
    uint64_t ps = (p3 % 8ull) ? ((p3 + 7ull) / 8ull) * 8ull : p3;
    if (ps > (1ull << 19)) ps = 1ull << 19;
    float sf = (float)sd;
    uint32_t res_enc = (uint32_t)(ceilf(sf) + 1.0f);
    prm.scale[l]  = sf;
    prm.res[l]    = res_enc;
    prm.msize[l]  = (uint32_t)ps;
    prm.offset[l] = off;
    off += (uint32_t)ps;
  }

  dim3 grid((n + 255) / 256), block(256);
  size_t ws_needed = (size_t)NHASH * (size_t)n * sizeof(float2);

  if (ws_size >= ws_needed) {
    float2* tmp = (float2*)d_ws;
    // one pass per hashed level: only that level's 4 MB table is hot in L2
    for (int l = NDENSE; l < NLV; ++l) {
      hipLaunchKernelGGL(hash_level_kernel, grid, block, 0, stream,
                         positions, table + 2u * prm.offset[l],
                         tmp + (size_t)(l - NDENSE) * n,
                         prm.scale[l], prm.msize[l] - 1u, n);
    }
    ParamsD pd;
    for (int l = 0; l < NDENSE; ++l) {
      pd.scale[l] = prm.scale[l]; pd.res[l] = prm.res[l];
      pd.msize[l] = prm.msize[l]; pd.offset[l] = prm.offset[l];
    }
    hipLaunchKernelGGL(dense_pack_kernel, grid, block, 0, stream,
                       positions, table, tmp, out, pd, n);
  } else {
    // ws too small: correct (slower) single-kernel fallback
    hipLaunchKernelGGL(hash_enc_kernel, grid, block, 0, stream,
                       positions, table, out, prm, n);
  }
}

// Round 5
// 493.402 us; speedup vs baseline: 1.1295x; 1.1295x over previous
//
#include <hip/hip_runtime.h>
#include <math.h>
#include <stdint.h>

#define NLV 16
#define NDENSE 6
#define NHASH 10

typedef float evf2 __attribute__((ext_vector_type(2)));
typedef float evf4 __attribute__((ext_vector_type(4)));

struct Params {          // all 16 levels (fallback kernel)
  float scale[NLV];
  uint32_t res[NLV];
  uint32_t msize[NLV];
  uint32_t offset[NLV];
};

struct ParamsD {         // dense levels 0..5
  float scale[NDENSE];
  uint32_t res[NDENSE];
  uint32_t msize[NDENSE];
  uint32_t offset[NDENSE];
};

__device__ __forceinline__ float ntload(const float* p) {
  return __builtin_nontemporal_load(p);
}

// ---------- per-hashed-level pass: tmp[p] = feat2(level) ----------
__global__ __launch_bounds__(256) void hash_level_kernel(
    const float* __restrict__ positions,
    const float* __restrict__ tbl,      // table already offset to this level
    float2* __restrict__ tmp,
    float scale, uint32_t mask, int n)
{
  int p = blockIdx.x * 256 + threadIdx.x;
  if (p >= n) return;

  // nt: positions are streamed once per pass — don't evict the table from L2
  float x = (ntload(positions + 3*p+0) + 1.0f) * 0.5f;
  float y = (ntload(positions + 3*p+1) + 1.0f) * 0.5f;
  float z = (ntload(positions + 3*p+2) + 1.0f) * 0.5f;

  float px = x * scale + 0.5f;
  float py = y * scale + 0.5f;
  float pz = z * scale + 0.5f;
  float fx = floorf(px), fy = floorf(py), fz = floorf(pz);
  float tx = px - fx, ty = py - fy, tz = pz - fz;
  uint32_t gx = (uint32_t)fx, gy = (uint32_t)fy, gz = (uint32_t)fz;

  float wxa = 1.0f - tx, wxb = tx;
  float wy_[2] = {1.0f - ty, ty};
  float wz_[2] = {1.0f - tz, tz};

  float f0 = 0.0f, f1 = 0.0f;

  // fast_hash uses prime 1 on x: for even gx the two x-corners are h and h^1
  // -> one aligned float4 covers both. Branch hoisted so it exec-masks.
  if ((gx & 1u) == 0u) {
    #pragma unroll
    for (int cyz = 0; cyz < 4; ++cyz) {
      uint32_t cy = gy + (cyz & 1u);
      uint32_t cz = gz + (cyz >> 1);
      uint32_t hy = (cy * 2654435761u) ^ (cz * 805459861u);
      uint32_t ha = (gx ^ hy) & mask;
      float wyz = wy_[cyz & 1u] * wz_[cyz >> 1];
      float wa = wxa * wyz, wb = wxb * wyz;
      const float4 t4 = *reinterpret_cast<const float4*>(tbl + 2u * (ha & ~1u));
      float2 ta, tb;
      if (ha & 1u) { ta.x = t4.z; ta.y = t4.w; tb.x = t4.x; tb.y = t4.y; }
      else         { ta.x = t4.x; ta.y = t4.y; tb.x = t4.z; tb.y = t4.w; }
      f0 += wa * ta.x; f1 += wa * ta.y;
      f0 += wb * tb.x; f1 += wb * tb.y;
    }
  } else {
    #pragma unroll
    for (int cyz = 0; cyz < 4; ++cyz) {
      uint32_t cy = gy + (cyz & 1u);
      uint32_t cz = gz + (cyz >> 1);
      uint32_t hy = (cy * 2654435761u) ^ (cz * 805459861u);
      uint32_t ha = (gx ^ hy) & mask;
      uint32_t hb = ((gx + 1u) ^ hy) & mask;
      float wyz = wy_[cyz & 1u] * wz_[cyz >> 1];
      float wa = wxa * wyz, wb = wxb * wyz;
      const float2 ta = *reinterpret_cast<const float2*>(tbl + 2u * ha);
      const float2 tb = *reinterpret_cast<const float2*>(tbl + 2u * hb);
      f0 += wa * ta.x; f1 += wa * ta.y;
      f0 += wb * tb.x; f1 += wb * tb.y;
    }
  }

  // nt store: full 512 B/wave contiguous per instruction -> no amplification
  evf2 v; v.x = f0; v.y = f1;
  __builtin_nontemporal_store(v, reinterpret_cast<evf2*>(tmp + p));
}

// ---------- dense levels inline + pack everything ----------
__global__ __launch_bounds__(256) void dense_pack_kernel(
    const float* __restrict__ positions,
    const float* __restrict__ table,
    const float2* __restrict__ tmp,     // [NHASH][n] level-major
    float* __restrict__ out,
    ParamsD prm, int n)
{
  int p = blockIdx.x * 256 + threadIdx.x;
  if (p >= n) return;

  float x = (ntload(positions + 3*p+0) + 1.0f) * 0.5f;
  float y = (ntload(positions + 3*p+1) + 1.0f) * 0.5f;
  float z = (ntload(positions + 3*p+2) + 1.0f) * 0.5f;

  float acc[2*NDENSE];

  #pragma unroll
  for (int l = 0; l < NDENSE; ++l) {
    const float s = prm.scale[l];
    const uint32_t res = prm.res[l];
    const uint32_t ms = prm.msize[l];
    const float* __restrict__ tbl = table + 2u * prm.offset[l];
    const uint32_t res2 = res * res;

    float px = x * s + 0.5f;
    float py = y * s + 0.5f;
    float pz = z * s + 0.5f;
    float fx = floorf(px), fy = floorf(py), fz = floorf(pz);
    float tx = px - fx, ty = py - fy, tz = pz - fz;
    uint32_t gx = (uint32_t)fx, gy = (uint32_t)fy, gz = (uint32_t)fz;

    float wxa = 1.0f - tx, wxb = tx;
    float wy_[2] = {1.0f - ty, ty};
    float wz_[2] = {1.0f - tz, tz};

    float f0 = 0.0f, f1 = 0.0f;
    // x-pair corners are adjacent dense indices (h, h+1): one float4 per pair.
    #pragma unroll
    for (int cyz = 0; cyz < 4; ++cyz) {
      uint32_t cy = gy + (cyz & 1u);
      uint32_t cz = gz + ((cyz >> 1) & 1u);
      uint32_t h = gx + cy * res + cz * res2;   // corner a; h < 2*ms always
      if (h >= ms) h -= ms;
      float wyz = wy_[cyz & 1u] * wz_[(cyz >> 1) & 1u];
      float2 ta, tb;
      if (h + 1u < ms) {                        // common: corner b = h+1
        const float4 t4 = *reinterpret_cast<const float4*>(tbl + 2u * h);
        ta.x = t4.x; ta.y = t4.y; tb.x = t4.z; tb.y = t4.w;
      } else {                                  // rare: corner b wraps to 0
        ta = *reinterpret_cast<const float2*>(tbl + 2u * h);
        tb = *reinterpret_cast<const float2*>(tbl);
      }
      float wa = wxa * wyz, wb = wxb * wyz;
      f0 += wa * ta.x; f1 += wa * ta.y;
      f0 += wb * tb.x; f1 += wb * tb.y;
    }
    acc[2*l]   = f0;
    acc[2*l+1] = f1;
  }

  // hashed-level temps: coalesced nt loads (streamed once)
  evf2 hv[NHASH];
  #pragma unroll
  for (int j = 0; j < NHASH; ++j)
    hv[j] = __builtin_nontemporal_load(
        reinterpret_cast<const evf2*>(tmp + (size_t)j * n + p));

  // NORMAL stores (R4 lesson: nt + strided-per-instruction = 4x write
  // amplification; L2 must merge the 8 partial line-writes).
  float4* o = reinterpret_cast<float4*>(out + (size_t)p * 32u);
  o[0] = make_float4(acc[0], acc[1], acc[2],  acc[3]);
  o[1] = make_float4(acc[4], acc[5], acc[6],  acc[7]);
  o[2] = make_float4(acc[8], acc[9], acc[10], acc[11]);
  #pragma unroll
  for (int j = 0; j < 5; ++j)
    o[3 + j] = make_float4(hv[2*j].x, hv[2*j].y, hv[2*j+1].x, hv[2*j+1].y);
}

// ---------- fallback: single fused kernel ----------
__global__ __launch_bounds__(256) void hash_enc_kernel(
    const float* __restrict__ positions,
    const float* __restrict__ table,
    float* __restrict__ out,
    Params prm, int n)
{
  int p = blockIdx.x * 256 + threadIdx.x;
  if (p >= n) return;

  float x = (positions[3*p+0] + 1.0f) * 0.5f;
  float y = (positions[3*p+1] + 1.0f) * 0.5f;
  float z = (positions[3*p+2] + 1.0f) * 0.5f;

  float acc[32];

  #pragma unroll
  for (int l = 0; l < NLV; ++l) {
    const float s = prm.scale[l];
    const uint32_t res = prm.res[l];
    const uint32_t ms = prm.msize[l];
    const uint32_t off = prm.offset[l];

    float px = x * s + 0.5f;
    float py = y * s + 0.5f;
    float pz = z * s + 0.5f;
    float fx = floorf(px), fy = floorf(py), fz = floorf(pz);
    float tx = px - fx, ty = py - fy, tz = pz - fz;
    uint32_t gx = (uint32_t)fx, gy = (uint32_t)fy, gz = (uint32_t)fz;

    float wx[2] = {1.0f - tx, tx};
    float wy[2] = {1.0f - ty, ty};
    float wz[2] = {1.0f - tz, tz};

    float f0 = 0.0f, f1 = 0.0f;
    #pragma unroll
    for (int c = 0; c < 8; ++c) {
      uint32_t cx = gx + (c & 1u);
      uint32_t cy = gy + ((c >> 1) & 1u);
      uint32_t cz = gz + ((c >> 2) & 1u);
      uint32_t h;
      if (l < NDENSE) {
        h = cx + cy * res + cz * res * res;
        if (h >= ms) h -= ms;
      } else {
        h = cx ^ (cy * 2654435761u) ^ (cz * 805459861u);
        h &= (ms - 1u);
      }
      float w = (wx[c & 1u] * wy[(c >> 1) & 1u]) * wz[(c >> 2) & 1u];
      const float2 t = *reinterpret_cast<const float2*>(table + 2u * (h + off));
      f0 += w * t.x;
      f1 += w * t.y;
    }
    acc[2*l]   = f0;
    acc[2*l+1] = f1;
  }

  float4* o = reinterpret_cast<float4*>(out + (size_t)p * 32u);
  #pragma unroll
  for (int k = 0; k < 8; ++k)
    o[k] = make_float4(acc[4*k+0], acc[4*k+1], acc[4*k+2], acc[4*k+3]);
}

extern "C" void kernel_launch(void* const* d_in, const int* in_sizes, int n_in,
                              void* d_out, int out_size, void* d_ws, size_t ws_size,
                              hipStream_t stream) {
  const float* positions = (const float*)d_in[0];
  const float* table     = (const float*)d_in[1];
  float* out             = (float*)d_out;
  int n = in_sizes[0] / 3;

  // Level metadata, exactly mirroring the reference (f64 exp/log; f32 cast
  // for the encode-path scale; level 5 is dense with res=65 due to the
  // B_SCALE^5 = 4.0000007 float quirk).
  Params prm;
  const double lnb = log(1.3195079565048218);
  uint32_t off = 0;
  for (int l = 0; l < NLV; ++l) {
    double sd = 16.0 * exp((double)l * lnb) - 1.0;
    uint32_t res_meta = (uint32_t)ceil(sd) + 1u;
    uint64_t p3 = (uint64_t)res_meta * res_meta * res_meta;
    uint64_t ps = (p3 % 8ull) ? ((p3 + 7ull) / 8ull) * 8ull : p3;
    if (ps > (1ull << 19)) ps = 1ull << 19;
    float sf = (float)sd;
    uint32_t res_enc = (uint32_t)(ceilf(sf) + 1.0f);
    prm.scale[l]  = sf;
    prm.res[l]    = res_enc;
    prm.msize[l]  = (uint32_t)ps;
    prm.offset[l] = off;
    off += (uint32_t)ps;
  }

  dim3 grid((n + 255) / 256), block(256);
  size_t ws_needed = (size_t)NHASH * (size_t)n * sizeof(float2);

  if (ws_size >= ws_needed) {
    float2* tmp = (float2*)d_ws;
    // one pass per hashed level: only that level's 4 MB table is hot in L2
    for (int l = NDENSE; l < NLV; ++l) {
      hipLaunchKernelGGL(hash_level_kernel, grid, block, 0, stream,
                         positions, table + 2u * prm.offset[l],
                         tmp + (size_t)(l - NDENSE) * n,
                         prm.scale[l], prm.msize[l] - 1u, n);
    }
    ParamsD pd;
    for (int l = 0; l < NDENSE; ++l) {
      pd.scale[l] = prm.scale[l]; pd.res[l] = prm.res[l];
      pd.msize[l] = prm.msize[l]; pd.offset[l] = prm.offset[l];
    }
    hipLaunchKernelGGL(dense_pack_kernel, grid, block, 0, stream,
                       positions, table, tmp, out, pd, n);
  } else {
    // ws too small: correct (slower) single-kernel fallback
    hipLaunchKernelGGL(hash_enc_kernel, grid, block, 0, stream,
                       positions, table, out, prm, n);
  }
}

// Round 6
// 485.882 us; speedup vs baseline: 1.1470x; 1.0155x over previous
//
#include <hip/hip_runtime.h>
#include <math.h>
#include <stdint.h>

#define NLV 16
#define NDENSE 6
#define NHASH 10

typedef float evf2 __attribute__((ext_vector_type(2)));

struct Params {          // all 16 levels (fallback kernel)
  float scale[NLV];
  uint32_t res[NLV];
  uint32_t msize[NLV];
  uint32_t offset[NLV];
};

struct ParamsD {         // dense levels 0..5
  float scale[NDENSE];
  uint32_t res[NDENSE];
  uint32_t msize[NDENSE];
  uint32_t offset[NDENSE];
};

__device__ __forceinline__ float ntload(const float* p) {
  return __builtin_nontemporal_load(p);
}

// ---------- per-hashed-level pass: tmp[p] = feat2(level), 2 pts/thread ----------
__global__ __launch_bounds__(256) void hash_level_kernel(
    const float* __restrict__ positions,
    const float* __restrict__ tbl,      // table already offset to this level
    float2* __restrict__ tmp,
    float scale, uint32_t mask, int n)
{
  int t = blockIdx.x * 256 + threadIdx.x;
  int p0 = t * 2;
  if (p0 >= n) return;

  // nt: positions streamed once per pass — keep the 4 MB table in L2
  float xx[2], yy[2], zz[2];
  {
    evf2 a = __builtin_nontemporal_load(reinterpret_cast<const evf2*>(positions + 3*p0));
    evf2 b = __builtin_nontemporal_load(reinterpret_cast<const evf2*>(positions + 3*p0 + 2));
    evf2 c = __builtin_nontemporal_load(reinterpret_cast<const evf2*>(positions + 3*p0 + 4));
    xx[0] = a.x; yy[0] = a.y; zz[0] = b.x;
    xx[1] = b.y; yy[1] = c.x; zz[1] = c.y;
  }

  float r0[2], r1[2];
  #pragma unroll
  for (int q = 0; q < 2; ++q) {
    float x = (xx[q] + 1.0f) * 0.5f;
    float y = (yy[q] + 1.0f) * 0.5f;
    float z = (zz[q] + 1.0f) * 0.5f;

    float px = x * scale + 0.5f;
    float py = y * scale + 0.5f;
    float pz = z * scale + 0.5f;
    float fx = floorf(px), fy = floorf(py), fz = floorf(pz);
    float tx = px - fx, ty = py - fy, tz = pz - fz;
    uint32_t gx = (uint32_t)fx, gy = (uint32_t)fy, gz = (uint32_t)fz;

    float wxa = 1.0f - tx, wxb = tx;
    float wy_[2] = {1.0f - ty, ty};
    float wz_[2] = {1.0f - tz, tz};

    float f0 = 0.0f, f1 = 0.0f;

    // fast_hash uses prime 1 on x: even gx -> x-pair is (h, h^1), one float4.
    if ((gx & 1u) == 0u) {
      #pragma unroll
      for (int cyz = 0; cyz < 4; ++cyz) {
        uint32_t cy = gy + (cyz & 1u);
        uint32_t cz = gz + (cyz >> 1);
        uint32_t hy = (cy * 2654435761u) ^ (cz * 805459861u);
        uint32_t ha = (gx ^ hy) & mask;
        float wyz = wy_[cyz & 1u] * wz_[cyz >> 1];
        float wa = wxa * wyz, wb = wxb * wyz;
        const float4 t4 = *reinterpret_cast<const float4*>(tbl + 2u * (ha & ~1u));
        float2 ta, tb;
        if (ha & 1u) { ta.x = t4.z; ta.y = t4.w; tb.x = t4.x; tb.y = t4.y; }
        else         { ta.x = t4.x; ta.y = t4.y; tb.x = t4.z; tb.y = t4.w; }
        f0 += wa * ta.x; f1 += wa * ta.y;
        f0 += wb * tb.x; f1 += wb * tb.y;
      }
    } else {
      #pragma unroll
      for (int cyz = 0; cyz < 4; ++cyz) {
        uint32_t cy = gy + (cyz & 1u);
        uint32_t cz = gz + (cyz >> 1);
        uint32_t hy = (cy * 2654435761u) ^ (cz * 805459861u);
        uint32_t ha = (gx ^ hy) & mask;
        uint32_t hb = ((gx + 1u) ^ hy) & mask;
        float wyz = wy_[cyz & 1u] * wz_[cyz >> 1];
        float wa = wxa * wyz, wb = wxb * wyz;
        const float2 ta = *reinterpret_cast<const float2*>(tbl + 2u * ha);
        const float2 tb = *reinterpret_cast<const float2*>(tbl + 2u * hb);
        f0 += wa * ta.x; f1 += wa * ta.y;
        f0 += wb * tb.x; f1 += wb * tb.y;
      }
    }
    r0[q] = f0; r1[q] = f1;
  }

  // nt stores: contiguous full-line-per-wave stream, keep L2 for the table
  evf2 v0; v0.x = r0[0]; v0.y = r1[0];
  __builtin_nontemporal_store(v0, reinterpret_cast<evf2*>(tmp + p0));
  if (p0 + 1 < n) {
    evf2 v1; v1.x = r0[1]; v1.y = r1[1];
    __builtin_nontemporal_store(v1, reinterpret_cast<evf2*>(tmp + p0 + 1));
  }
}

// ---------- dense levels inline + pack everything, 4 pts/thread ----------
__global__ __launch_bounds__(256) void dense_pack_kernel(
    const float* __restrict__ positions,
    const float* __restrict__ table,
    const float2* __restrict__ tmp,     // [NHASH][n] level-major
    float* __restrict__ out,
    ParamsD prm, int n)
{
  int t = blockIdx.x * 256 + threadIdx.x;
  int p0 = t * 4;
  if (p0 >= n) return;
  // n is a multiple of 4 in this harness (guard above covers exact fit)

  // 12 floats = 3 aligned float4 loads (48 B per thread, fully coalesced)
  const float4 pA = *reinterpret_cast<const float4*>(positions + 3*p0);
  const float4 pB = *reinterpret_cast<const float4*>(positions + 3*p0 + 4);
  const float4 pC = *reinterpret_cast<const float4*>(positions + 3*p0 + 8);
  float xs[4] = {pA.x, pA.w, pB.z, pC.y};
  float ys[4] = {pA.y, pB.x, pB.w, pC.z};
  float zs[4] = {pA.z, pB.y, pC.x, pC.w};

  float acc[4][2*NDENSE];

  #pragma unroll
  for (int l = 0; l < NDENSE; ++l) {
    const float s = prm.scale[l];
    const uint32_t res = prm.res[l];
    const uint32_t ms = prm.msize[l];
    const float* __restrict__ tbl = table + 2u * prm.offset[l];
    const uint32_t res2 = res * res;

    // 4 independent points: 32 independent float2 gathers in flight
    #pragma unroll
    for (int q = 0; q < 4; ++q) {
      float x = (xs[q] + 1.0f) * 0.5f;
      float y = (ys[q] + 1.0f) * 0.5f;
      float z = (zs[q] + 1.0f) * 0.5f;
      float px = x * s + 0.5f;
      float py = y * s + 0.5f;
      float pz = z * s + 0.5f;
      float fx = floorf(px), fy = floorf(py), fz = floorf(pz);
      float tx = px - fx, ty = py - fy, tz = pz - fz;
      uint32_t gx = (uint32_t)fx, gy = (uint32_t)fy, gz = (uint32_t)fz;

      float wx_[2] = {1.0f - tx, tx};
      float wy_[2] = {1.0f - ty, ty};
      float wz_[2] = {1.0f - tz, tz};

      float f0 = 0.0f, f1 = 0.0f;
      #pragma unroll
      for (int c = 0; c < 8; ++c) {
        uint32_t cx = gx + (c & 1u);
        uint32_t cy = gy + ((c >> 1) & 1u);
        uint32_t cz = gz + ((c >> 2) & 1u);
        uint32_t h = cx + cy * res + cz * res2;   // h < 2*ms always
        if (h >= ms) h -= ms;
        float w = (wx_[c & 1u] * wy_[(c >> 1) & 1u]) * wz_[(c >> 2) & 1u];
        const float2 tv = *reinterpret_cast<const float2*>(tbl + 2u * h);
        f0 += w * tv.x;
        f1 += w * tv.y;
      }
      acc[q][2*l]   = f0;
      acc[q][2*l+1] = f1;
    }
  }

  #pragma unroll
  for (int q = 0; q < 4; ++q) {
    int p = p0 + q;
    // hashed-level temps: coalesced nt loads (streamed once)
    evf2 hv[NHASH];
    #pragma unroll
    for (int j = 0; j < NHASH; ++j)
      hv[j] = __builtin_nontemporal_load(
          reinterpret_cast<const evf2*>(tmp + (size_t)j * n + p));

    float4* o = reinterpret_cast<float4*>(out + (size_t)p * 32u);
    o[0] = make_float4(acc[q][0], acc[q][1], acc[q][2],  acc[q][3]);
    o[1] = make_float4(acc[q][4], acc[q][5], acc[q][6],  acc[q][7]);
    o[2] = make_float4(acc[q][8], acc[q][9], acc[q][10], acc[q][11]);
    #pragma unroll
    for (int j = 0; j < 5; ++j)
      o[3 + j] = make_float4(hv[2*j].x, hv[2*j].y, hv[2*j+1].x, hv[2*j+1].y);
  }
}

// ---------- fallback: single fused kernel ----------
__global__ __launch_bounds__(256) void hash_enc_kernel(
    const float* __restrict__ positions,
    const float* __restrict__ table,
    float* __restrict__ out,
    Params prm, int n)
{
  int p = blockIdx.x * 256 + threadIdx.x;
  if (p >= n) return;

  float x = (positions[3*p+0] + 1.0f) * 0.5f;
  float y = (positions[3*p+1] + 1.0f) * 0.5f;
  float z = (positions[3*p+2] + 1.0f) * 0.5f;

  float acc[32];

  #pragma unroll
  for (int l = 0; l < NLV; ++l) {
    const float s = prm.scale[l];
    const uint32_t res = prm.res[l];
    const uint32_t ms = prm.msize[l];
    const uint32_t off = prm.offset[l];

    float px = x * s + 0.5f;
    float py = y * s + 0.5f;
    float pz = z * s + 0.5f;
    float fx = floorf(px), fy = floorf(py), fz = floorf(pz);
    float tx = px - fx, ty = py - fy, tz = pz - fz;
    uint32_t gx = (uint32_t)fx, gy = (uint32_t)fy, gz = (uint32_t)fz;

    float wx[2] = {1.0f - tx, tx};
    float wy[2] = {1.0f - ty, ty};
    float wz[2] = {1.0f - tz, tz};

    float f0 = 0.0f, f1 = 0.0f;
    #pragma unroll
    for (int c = 0; c < 8; ++c) {
      uint32_t cx = gx + (c & 1u);
      uint32_t cy = gy + ((c >> 1) & 1u);
      uint32_t cz = gz + ((c >> 2) & 1u);
      uint32_t h;
      if (l < NDENSE) {
        h = cx + cy * res + cz * res * res;
        if (h >= ms) h -= ms;
      } else {
        h = cx ^ (cy * 2654435761u) ^ (cz * 805459861u);
        h &= (ms - 1u);
      }
      float w = (wx[c & 1u] * wy[(c >> 1) & 1u]) * wz[(c >> 2) & 1u];
      const float2 t = *reinterpret_cast<const float2*>(table + 2u * (h + off));
      f0 += w * t.x;
      f1 += w * t.y;
    }
    acc[2*l]   = f0;
    acc[2*l+1] = f1;
  }

  float4* o = reinterpret_cast<float4*>(out + (size_t)p * 32u);
  #pragma unroll
  for (int k = 0; k < 8; ++k)
    o[k] = make_float4(acc[4*k+0], acc[4*k+1], acc[4*k+2], acc[4*k+3]);
}

extern "C" void kernel_launch(void* const* d_in, const int* in_sizes, int n_in,
                              void* d_out, int out_size, void* d_ws, size_t ws_size,
                              hipStream_t stream) {
  const float* positions = (const float*)d_in[0];
  const float* table     = (const float*)d_in[1];
  float* out             = (float*)d_out;
  int n = in_sizes[0] / 3;

  // Level metadata, exactly mirroring the reference (f64 exp/log; f32 cast
  // for the encode-path scale; level 5 is dense with res=65 due to the
  // B_SCALE^5 = 4.0000007 float quirk).
  Params prm;
  const double lnb = log(1.3195079565048218);
  uint32_t off = 0;
  for (int l = 0; l < NLV; ++l) {
    double sd = 16.0 * exp((double)l * lnb) - 1.0;
    uint32_t res_meta = (uint32_t)ceil(sd) + 1u;
    uint64_t p3 = (uint64_t)res_meta * res_meta * res_meta;
    uint64_t ps = (p3 % 8ull) ? ((p3 + 7ull) / 8ull) * 8ull : p3;
    if (ps > (1ull << 19)) ps = 1ull << 19;
    float sf = (float)sd;
    uint32_t res_enc = (uint32_t)(ceilf(sf) + 1.0f);
    prm.scale[l]  = sf;
    prm.res[l]    = res_enc;
    prm.msize[l]  = (uint32_t)ps;
    prm.offset[l] = off;
    off += (uint32_t)ps;
  }

  size_t ws_needed = (size_t)NHASH * (size_t)n * sizeof(float2);

  if (ws_size >= ws_needed && (n % 4) == 0) {
    float2* tmp = (float2*)d_ws;
    dim3 block(256);
    dim3 ghash((n/2 + 255) / 256);
    // one pass per hashed level: only that level's 4 MB table is hot in L2
    for (int l = NDENSE; l < NLV; ++l) {
      hipLaunchKernelGGL(hash_level_kernel, ghash, block, 0, stream,
                         positions, table + 2u * prm.offset[l],
                         tmp + (size_t)(l - NDENSE) * n,
                         prm.scale[l], prm.msize[l] - 1u, n);
    }
    ParamsD pd;
    for (int l = 0; l < NDENSE; ++l) {
      pd.scale[l] = prm.scale[l]; pd.res[l] = prm.res[l];
      pd.msize[l] = prm.msize[l]; pd.offset[l] = prm.offset[l];
    }
    dim3 gpack((n/4 + 255) / 256);
    hipLaunchKernelGGL(dense_pack_kernel, gpack, block, 0, stream,
                       positions, table, tmp, out, pd, n);
  } else {
    // fallback: correct single-kernel path
    dim3 grid((n + 255) / 256), block(256);
    hipLaunchKernelGGL(hash_enc_kernel, grid, block, 0, stream,
                       positions, table, out, prm, n);
  }
}

// Round 7
// 485.124 us; speedup vs baseline: 1.1488x; 1.0016x over previous
//
#include <hip/hip_runtime.h>
#include <math.h>
#include <stdint.h>

#define NLV 16
#define NDENSE 6
#define NHASH 10

typedef float evf2 __attribute__((ext_vector_type(2)));

struct Params {          // all 16 levels (fallback kernel)
  float scale[NLV];
  uint32_t res[NLV];
  uint32_t msize[NLV];
  uint32_t offset[NLV];
};

struct ParamsD {         // dense levels 0..5
  float scale[NDENSE];
  uint32_t res[NDENSE];
  uint32_t msize[NDENSE];
  uint32_t offset[NDENSE];
};

__device__ __forceinline__ float ntload(const float* p) {
  return __builtin_nontemporal_load(p);
}

// ---------- per-hashed-level pass: tmp[p] = feat2(level), 2 pts/thread ----------
__global__ __launch_bounds__(256) void hash_level_kernel(
    const float* __restrict__ positions,
    const float* __restrict__ tbl,      // table already offset to this level
    float2* __restrict__ tmp,
    float scale, uint32_t mask, int n)
{
  int t = blockIdx.x * 256 + threadIdx.x;
  int p0 = t * 2;
  if (p0 >= n) return;

  // nt: positions streamed once per pass — keep the 4 MB table in L2
  float xx[2], yy[2], zz[2];
  {
    evf2 a = __builtin_nontemporal_load(reinterpret_cast<const evf2*>(positions + 3*p0));
    evf2 b = __builtin_nontemporal_load(reinterpret_cast<const evf2*>(positions + 3*p0 + 2));
    evf2 c = __builtin_nontemporal_load(reinterpret_cast<const evf2*>(positions + 3*p0 + 4));
    xx[0] = a.x; yy[0] = a.y; zz[0] = b.x;
    xx[1] = b.y; yy[1] = c.x; zz[1] = c.y;
  }

  float r0[2], r1[2];
  #pragma unroll
  for (int q = 0; q < 2; ++q) {
    float x = (xx[q] + 1.0f) * 0.5f;
    float y = (yy[q] + 1.0f) * 0.5f;
    float z = (zz[q] + 1.0f) * 0.5f;

    float px = x * scale + 0.5f;
    float py = y * scale + 0.5f;
    float pz = z * scale + 0.5f;
    float fx = floorf(px), fy = floorf(py), fz = floorf(pz);
    float tx = px - fx, ty = py - fy, tz = pz - fz;
    uint32_t gx = (uint32_t)fx, gy = (uint32_t)fy, gz = (uint32_t)fz;

    float wxa = 1.0f - tx, wxb = tx;
    float wy_[2] = {1.0f - ty, ty};
    float wz_[2] = {1.0f - tz, tz};

    float f0 = 0.0f, f1 = 0.0f;

    // fast_hash uses prime 1 on x: even gx -> x-pair is (h, h^1), one float4.
    if ((gx & 1u) == 0u) {
      #pragma unroll
      for (int cyz = 0; cyz < 4; ++cyz) {
        uint32_t cy = gy + (cyz & 1u);
        uint32_t cz = gz + (cyz >> 1);
        uint32_t hy = (cy * 2654435761u) ^ (cz * 805459861u);
        uint32_t ha = (gx ^ hy) & mask;
        float wyz = wy_[cyz & 1u] * wz_[cyz >> 1];
        float wa = wxa * wyz, wb = wxb * wyz;
        const float4 t4 = *reinterpret_cast<const float4*>(tbl + 2u * (ha & ~1u));
        float2 ta, tb;
        if (ha & 1u) { ta.x = t4.z; ta.y = t4.w; tb.x = t4.x; tb.y = t4.y; }
        else         { ta.x = t4.x; ta.y = t4.y; tb.x = t4.z; tb.y = t4.w; }
        f0 += wa * ta.x; f1 += wa * ta.y;
        f0 += wb * tb.x; f1 += wb * tb.y;
      }
    } else {
      #pragma unroll
      for (int cyz = 0; cyz < 4; ++cyz) {
        uint32_t cy = gy + (cyz & 1u);
        uint32_t cz = gz + (cyz >> 1);
        uint32_t hy = (cy * 2654435761u) ^ (cz * 805459861u);
        uint32_t ha = (gx ^ hy) & mask;
        uint32_t hb = ((gx + 1u) ^ hy) & mask;
        float wyz = wy_[cyz & 1u] * wz_[cyz >> 1];
        float wa = wxa * wyz, wb = wxb * wyz;
        const float2 ta = *reinterpret_cast<const float2*>(tbl + 2u * ha);
        const float2 tb = *reinterpret_cast<const float2*>(tbl + 2u * hb);
        f0 += wa * ta.x; f1 += wa * ta.y;
        f0 += wb * tb.x; f1 += wb * tb.y;
      }
    }
    r0[q] = f0; r1[q] = f1;
  }

  evf2 v0; v0.x = r0[0]; v0.y = r1[0];
  __builtin_nontemporal_store(v0, reinterpret_cast<evf2*>(tmp + p0));
  if (p0 + 1 < n) {
    evf2 v1; v1.x = r0[1]; v1.y = r1[1];
    __builtin_nontemporal_store(v1, reinterpret_cast<evf2*>(tmp + p0 + 1));
  }
}

// ---------- dense levels 0..5 -> tmp slots 10..15 (pure gather kernel) ----------
__global__ __launch_bounds__(256) void dense_kernel(
    const float* __restrict__ positions,
    const float* __restrict__ table,
    float2* __restrict__ tmp,           // [16][n] float2, we write slots 10..15
    ParamsD prm, int n)
{
  int p = blockIdx.x * 256 + threadIdx.x;
  if (p >= n) return;

  float x = (ntload(positions + 3*p+0) + 1.0f) * 0.5f;
  float y = (ntload(positions + 3*p+1) + 1.0f) * 0.5f;
  float z = (ntload(positions + 3*p+2) + 1.0f) * 0.5f;

  #pragma unroll
  for (int l = 0; l < NDENSE; ++l) {
    const float s = prm.scale[l];
    const uint32_t res = prm.res[l];
    const uint32_t ms = prm.msize[l];
    const float* __restrict__ tbl = table + 2u * prm.offset[l];
    const uint32_t res2 = res * res;

    float px = x * s + 0.5f;
    float py = y * s + 0.5f;
    float pz = z * s + 0.5f;
    float fx = floorf(px), fy = floorf(py), fz = floorf(pz);
    float tx = px - fx, ty = py - fy, tz = pz - fz;
    uint32_t gx = (uint32_t)fx, gy = (uint32_t)fy, gz = (uint32_t)fz;

    float wxa = 1.0f - tx, wxb = tx;
    float wy_[2] = {1.0f - ty, ty};
    float wz_[2] = {1.0f - tz, tz};

    float f0 = 0.0f, f1 = 0.0f;
    // x-pair corners are adjacent dense indices (h, h+1): one float4 per pair.
    #pragma unroll
    for (int cyz = 0; cyz < 4; ++cyz) {
      uint32_t cy = gy + (cyz & 1u);
      uint32_t cz = gz + ((cyz >> 1) & 1u);
      uint32_t h = gx + cy * res + cz * res2;   // raw in [0, 2*ms)
      if (h >= ms) h -= ms;
      float wyz = wy_[cyz & 1u] * wz_[(cyz >> 1) & 1u];
      float2 ta, tb;
      if (h + 1u < ms) {                        // common: corner b = h+1
        const float4 t4 = *reinterpret_cast<const float4*>(tbl + 2u * h);
        ta.x = t4.x; ta.y = t4.y; tb.x = t4.z; tb.y = t4.w;
      } else {                                  // h == ms-1: corner b wraps to 0
        ta = *reinterpret_cast<const float2*>(tbl + 2u * h);
        tb = *reinterpret_cast<const float2*>(tbl);
      }
      float wa = wxa * wyz, wb = wxb * wyz;
      f0 += wa * ta.x; f1 += wa * ta.y;
      f0 += wb * tb.x; f1 += wb * tb.y;
    }
    evf2 v; v.x = f0; v.y = f1;
    __builtin_nontemporal_store(v,
        reinterpret_cast<evf2*>(tmp + (size_t)(NHASH + l) * n + p));
  }
}

// ---------- pure streaming pack: 16 slots -> [N,32] ----------
__global__ __launch_bounds__(256) void stream_pack_kernel(
    const float2* __restrict__ tmp,     // [16][n] float2
    float* __restrict__ out, int n)
{
  int p = blockIdx.x * 256 + threadIdx.x;
  if (p >= n) return;

  evf2 dv[NDENSE];
  #pragma unroll
  for (int j = 0; j < NDENSE; ++j)
    dv[j] = __builtin_nontemporal_load(
        reinterpret_cast<const evf2*>(tmp + (size_t)(NHASH + j) * n + p));
  evf2 hv[NHASH];
  #pragma unroll
  for (int j = 0; j < NHASH; ++j)
    hv[j] = __builtin_nontemporal_load(
        reinterpret_cast<const evf2*>(tmp + (size_t)j * n + p));

  // normal stores: 8 consecutive float4 per thread = full 128 B line, L2-merged
  float4* o = reinterpret_cast<float4*>(out + (size_t)p * 32u);
  #pragma unroll
  for (int j = 0; j < 3; ++j)
    o[j] = make_float4(dv[2*j].x, dv[2*j].y, dv[2*j+1].x, dv[2*j+1].y);
  #pragma unroll
  for (int j = 0; j < 5; ++j)
    o[3 + j] = make_float4(hv[2*j].x, hv[2*j].y, hv[2*j+1].x, hv[2*j+1].y);
}

// ---------- fallback A: dense levels inline + pack (R5 version) ----------
__global__ __launch_bounds__(256) void dense_pack_kernel(
    const float* __restrict__ positions,
    const float* __restrict__ table,
    const float2* __restrict__ tmp,     // [NHASH][n] level-major
    float* __restrict__ out,
    ParamsD prm, int n)
{
  int p = blockIdx.x * 256 + threadIdx.x;
  if (p >= n) return;

  float x = (ntload(positions + 3*p+0) + 1.0f) * 0.5f;
  float y = (ntload(positions + 3*p+1) + 1.0f) * 0.5f;
  float z = (ntload(positions + 3*p+2) + 1.0f) * 0.5f;

  float acc[2*NDENSE];

  #pragma unroll
  for (int l = 0; l < NDENSE; ++l) {
    const float s = prm.scale[l];
    const uint32_t res = prm.res[l];
    const uint32_t ms = prm.msize[l];
    const float* __restrict__ tbl = table + 2u * prm.offset[l];
    const uint32_t res2 = res * res;

    float px = x * s + 0.5f;
    float py = y * s + 0.5f;
    float pz = z * s + 0.5f;
    float fx = floorf(px), fy = floorf(py), fz = floorf(pz);
    float tx = px - fx, ty = py - fy, tz = pz - fz;
    uint32_t gx = (uint32_t)fx, gy = (uint32_t)fy, gz = (uint32_t)fz;

    float wxa = 1.0f - tx, wxb = tx;
    float wy_[2] = {1.0f - ty, ty};
    float wz_[2] = {1.0f - tz, tz};

    float f0 = 0.0f, f1 = 0.0f;
    #pragma unroll
    for (int cyz = 0; cyz < 4; ++cyz) {
      uint32_t cy = gy + (cyz & 1u);
      uint32_t cz = gz + ((cyz >> 1) & 1u);
      uint32_t h = gx + cy * res + cz * res2;
      if (h >= ms) h -= ms;
      float wyz = wy_[cyz & 1u] * wz_[(cyz >> 1) & 1u];
      float2 ta, tb;
      if (h + 1u < ms) {
        const float4 t4 = *reinterpret_cast<const float4*>(tbl + 2u * h);
        ta.x = t4.x; ta.y = t4.y; tb.x = t4.z; tb.y = t4.w;
      } else {
        ta = *reinterpret_cast<const float2*>(tbl + 2u * h);
        tb = *reinterpret_cast<const float2*>(tbl);
      }
      float wa = wxa * wyz, wb = wxb * wyz;
      f0 += wa * ta.x; f1 += wa * ta.y;
      f0 += wb * tb.x; f1 += wb * tb.y;
    }
    acc[2*l]   = f0;
    acc[2*l+1] = f1;
  }

  evf2 hv[NHASH];
  #pragma unroll
  for (int j = 0; j < NHASH; ++j)
    hv[j] = __builtin_nontemporal_load(
        reinterpret_cast<const evf2*>(tmp + (size_t)j * n + p));

  float4* o = reinterpret_cast<float4*>(out + (size_t)p * 32u);
  o[0] = make_float4(acc[0], acc[1], acc[2],  acc[3]);
  o[1] = make_float4(acc[4], acc[5], acc[6],  acc[7]);
  o[2] = make_float4(acc[8], acc[9], acc[10], acc[11]);
  #pragma unroll
  for (int j = 0; j < 5; ++j)
    o[3 + j] = make_float4(hv[2*j].x, hv[2*j].y, hv[2*j+1].x, hv[2*j+1].y);
}

// ---------- fallback B: single fused kernel ----------
__global__ __launch_bounds__(256) void hash_enc_kernel(
    const float* __restrict__ positions,
    const float* __restrict__ table,
    float* __restrict__ out,
    Params prm, int n)
{
  int p = blockIdx.x * 256 + threadIdx.x;
  if (p >= n) return;

  float x = (positions[3*p+0] + 1.0f) * 0.5f;
  float y = (positions[3*p+1] + 1.0f) * 0.5f;
  float z = (positions[3*p+2] + 1.0f) * 0.5f;

  float acc[32];

  #pragma unroll
  for (int l = 0; l < NLV; ++l) {
    const float s = prm.scale[l];
    const uint32_t res = prm.res[l];
    const uint32_t ms = prm.msize[l];
    const uint32_t off = prm.offset[l];

    float px = x * s + 0.5f;
    float py = y * s + 0.5f;
    float pz = z * s + 0.5f;
    float fx = floorf(px), fy = floorf(py), fz = floorf(pz);
    float tx = px - fx, ty = py - fy, tz = pz - fz;
    uint32_t gx = (uint32_t)fx, gy = (uint32_t)fy, gz = (uint32_t)fz;

    float wx[2] = {1.0f - tx, tx};
    float wy[2] = {1.0f - ty, ty};
    float wz[2] = {1.0f - tz, tz};

    float f0 = 0.0f, f1 = 0.0f;
    #pragma unroll
    for (int c = 0; c < 8; ++c) {
      uint32_t cx = gx + (c & 1u);
      uint32_t cy = gy + ((c >> 1) & 1u);
      uint32_t cz = gz + ((c >> 2) & 1u);
      uint32_t h;
      if (l < NDENSE) {
        h = cx + cy * res + cz * res * res;
        if (h >= ms) h -= ms;
      } else {
        h = cx ^ (cy * 2654435761u) ^ (cz * 805459861u);
        h &= (ms - 1u);
      }
      float w = (wx[c & 1u] * wy[(c >> 1) & 1u]) * wz[(c >> 2) & 1u];
      const float2 t = *reinterpret_cast<const float2*>(table + 2u * (h + off));
      f0 += w * t.x;
      f1 += w * t.y;
    }
    acc[2*l]   = f0;
    acc[2*l+1] = f1;
  }

  float4* o = reinterpret_cast<float4*>(out + (size_t)p * 32u);
  #pragma unroll
  for (int k = 0; k < 8; ++k)
    o[k] = make_float4(acc[4*k+0], acc[4*k+1], acc[4*k+2], acc[4*k+3]);
}

extern "C" void kernel_launch(void* const* d_in, const int* in_sizes, int n_in,
                              void* d_out, int out_size, void* d_ws, size_t ws_size,
                              hipStream_t stream) {
  const float* positions = (const float*)d_in[0];
  const float* table     = (const float*)d_in[1];
  float* out             = (float*)d_out;
  int n = in_sizes[0] / 3;

  // Level metadata, exactly mirroring the reference (f64 exp/log; f32 cast
  // for the encode-path scale; level 5 is dense with res=65 due to the
  // B_SCALE^5 = 4.0000007 float quirk).
  Params prm;
  const double lnb = log(1.3195079565048218);
  uint32_t off = 0;
  for (int l = 0; l < NLV; ++l) {
    double sd = 16.0 * exp((double)l * lnb) - 1.0;
    uint32_t res_meta = (uint32_t)ceil(sd) + 1u;
    uint64_t p3 = (uint64_t)res_meta * res_meta * res_meta;
    uint64_t ps = (p3 % 8ull) ? ((p3 + 7ull) / 8ull) * 8ull : p3;
    if (ps > (1ull << 19)) ps = 1ull << 19;
    float sf = (float)sd;
    uint32_t res_enc = (uint32_t)(ceilf(sf) + 1.0f);
    prm.scale[l]  = sf;
    prm.res[l]    = res_enc;
    prm.msize[l]  = (uint32_t)ps;
    prm.offset[l] = off;
    off += (uint32_t)ps;
  }
  ParamsD pd;
  for (int l = 0; l < NDENSE; ++l) {
    pd.scale[l] = prm.scale[l]; pd.res[l] = prm.res[l];
    pd.msize[l] = prm.msize[l]; pd.offset[l] = prm.offset[l];
  }

  dim3 block(256);
  dim3 gfull((n + 255) / 256);
  dim3 ghash((n/2 + 255) / 256);
  size_t ws16 = (size_t)NLV * (size_t)n * sizeof(float2);
  size_t ws10 = (size_t)NHASH * (size_t)n * sizeof(float2);

  if (ws_size >= ws16) {
    // three-stage: 10 hash passes + dense gather pass + pure streaming pack
    float2* tmp = (float2*)d_ws;
    for (int l = NDENSE; l < NLV; ++l) {
      hipLaunchKernelGGL(hash_level_kernel, ghash, block, 0, stream,
                         positions, table + 2u * prm.offset[l],
                         tmp + (size_t)(l - NDENSE) * n,
                         prm.scale[l], prm.msize[l] - 1u, n);
    }
    hipLaunchKernelGGL(dense_kernel, gfull, block, 0, stream,
                       positions, table, tmp, pd, n);
    hipLaunchKernelGGL(stream_pack_kernel, gfull, block, 0, stream,
                       tmp, out, n);
  } else if (ws_size >= ws10) {
    // two-stage fallback (R5 path)
    float2* tmp = (float2*)d_ws;
    for (int l = NDENSE; l < NLV; ++l) {
      hipLaunchKernelGGL(hash_level_kernel, ghash, block, 0, stream,
                         positions, table + 2u * prm.offset[l],
                         tmp + (size_t)(l - NDENSE) * n,
                         prm.scale[l], prm.msize[l] - 1u, n);
    }
    hipLaunchKernelGGL(dense_pack_kernel, gfull, block, 0, stream,
                       positions, table, tmp, out, pd, n);
  } else {
    hipLaunchKernelGGL(hash_enc_kernel, gfull, block, 0, stream,
                       positions, table, out, prm, n);
  }
}

// Round 9
// 448.694 us; speedup vs baseline: 1.2421x; 1.0812x over previous
//
#include <hip/hip_runtime.h>
#include <math.h>
#include <stdint.h>

#define NLV 16
#define NDENSE 6
#define NHASH 10
#define SORT_RES 32
#define NBINS (SORT_RES * SORT_RES * SORT_RES)   // 32768

typedef float evf2 __attribute__((ext_vector_type(2)));

struct Params {          // all 16 levels (fallback kernel)
  float scale[NLV];
  uint32_t res[NLV];
  uint32_t msize[NLV];
  uint32_t offset[NLV];
};

struct ParamsD {         // dense levels 0..5
  float scale[NDENSE];
  uint32_t res[NDENSE];
  uint32_t msize[NDENSE];
  uint32_t offset[NDENSE];
};

__device__ __forceinline__ float ntload(const float* p) {
  return __builtin_nontemporal_load(p);
}

// x-fastest linear cell key: waves of sorted points form x-runs, matching both
// the dense table's x-contiguity and the XOR-hash's x-window locality.
__device__ __forceinline__ uint32_t cell_key(float xr, float yr, float zr) {
  float x01 = (xr + 1.0f) * 0.5f;
  float y01 = (yr + 1.0f) * 0.5f;
  float z01 = (zr + 1.0f) * 0.5f;
  int cx = (int)(x01 * (float)SORT_RES);
  int cy = (int)(y01 * (float)SORT_RES);
  int cz = (int)(z01 * (float)SORT_RES);
  cx = cx < 0 ? 0 : (cx > SORT_RES-1 ? SORT_RES-1 : cx);
  cy = cy < 0 ? 0 : (cy > SORT_RES-1 ? SORT_RES-1 : cy);
  cz = cz < 0 ? 0 : (cz > SORT_RES-1 ? SORT_RES-1 : cz);
  return (uint32_t)(cx | (cy << 5) | (cz << 10));
}

// ---------------- sort machinery ----------------
__global__ __launch_bounds__(256) void zero_bins_kernel(uint32_t* bins) {
  int i = blockIdx.x * 256 + threadIdx.x;
  if (i < NBINS) bins[i] = 0u;
}

__global__ __launch_bounds__(256) void hist_kernel(
    const float* __restrict__ positions, uint32_t* __restrict__ bins, int n) {
  int p = blockIdx.x * 256 + threadIdx.x;
  if (p >= n) return;
  float x = positions[3*p], y = positions[3*p+1], z = positions[3*p+2];
  atomicAdd(&bins[cell_key(x, y, z)], 1u);
}

// single block, 1024 threads, 32 bins each: exclusive scan -> cursor
__global__ __launch_bounds__(1024) void scan_kernel(
    const uint32_t* __restrict__ bins, uint32_t* __restrict__ cursor) {
  __shared__ uint32_t lds[1024];
  int t = threadIdx.x;
  uint32_t local[32];
  uint32_t s = 0;
  #pragma unroll
  for (int j = 0; j < 32; ++j) { local[j] = bins[t*32 + j]; s += local[j]; }
  lds[t] = s;
  __syncthreads();
  for (int off = 1; off < 1024; off <<= 1) {
    uint32_t v = (t >= off) ? lds[t - off] : 0u;
    __syncthreads();
    lds[t] += v;
    __syncthreads();
  }
  uint32_t run = lds[t] - s;        // exclusive prefix of this thread's chunk
  #pragma unroll
  for (int j = 0; j < 32; ++j) { cursor[t*32 + j] = run; run += local[j]; }
}

__global__ __launch_bounds__(256) void scatter_kernel(
    const float* __restrict__ positions, uint32_t* __restrict__ cursor,
    float* __restrict__ sortedPos, uint32_t* __restrict__ origIdx, int n) {
  int p = blockIdx.x * 256 + threadIdx.x;
  if (p >= n) return;
  float x = positions[3*p], y = positions[3*p+1], z = positions[3*p+2];
  uint32_t k = cell_key(x, y, z);
  uint32_t dst = atomicAdd(&cursor[k], 1u);
  sortedPos[3*dst]   = x;
  sortedPos[3*dst+1] = y;
  sortedPos[3*dst+2] = z;
  origIdx[dst] = p;
}

// ---------- per-hashed-level pass: tmp[p] = feat2(level), 2 pts/thread ----------
__global__ __launch_bounds__(256) void hash_level_kernel(
    const float* __restrict__ positions,
    const float* __restrict__ tbl,      // table already offset to this level
    float2* __restrict__ tmp,
    float scale, uint32_t mask, int n)
{
  int t = blockIdx.x * 256 + threadIdx.x;
  int p0 = t * 2;
  if (p0 >= n) return;

  float xx[2], yy[2], zz[2];
  {
    evf2 a = __builtin_nontemporal_load(reinterpret_cast<const evf2*>(positions + 3*p0));
    evf2 b = __builtin_nontemporal_load(reinterpret_cast<const evf2*>(positions + 3*p0 + 2));
    evf2 c = __builtin_nontemporal_load(reinterpret_cast<const evf2*>(positions + 3*p0 + 4));
    xx[0] = a.x; yy[0] = a.y; zz[0] = b.x;
    xx[1] = b.y; yy[1] = c.x; zz[1] = c.y;
  }

  float r0[2], r1[2];
  #pragma unroll
  for (int q = 0; q < 2; ++q) {
    float x = (xx[q] + 1.0f) * 0.5f;
    float y = (yy[q] + 1.0f) * 0.5f;
    float z = (zz[q] + 1.0f) * 0.5f;

    float px = x * scale + 0.5f;
    float py = y * scale + 0.5f;
    float pz = z * scale + 0.5f;
    float fx = floorf(px), fy = floorf(py), fz = floorf(pz);
    float tx = px - fx, ty = py - fy, tz = pz - fz;
    uint32_t gx = (uint32_t)fx, gy = (uint32_t)fy, gz = (uint32_t)fz;

    float wxa = 1.0f - tx, wxb = tx;
    float wy_[2] = {1.0f - ty, ty};
    float wz_[2] = {1.0f - tz, tz};

    float f0 = 0.0f, f1 = 0.0f;

    if ((gx & 1u) == 0u) {
      #pragma unroll
      for (int cyz = 0; cyz < 4; ++cyz) {
        uint32_t cy = gy + (cyz & 1u);
        uint32_t cz = gz + (cyz >> 1);
        uint32_t hy = (cy * 2654435761u) ^ (cz * 805459861u);
        uint32_t ha = (gx ^ hy) & mask;
        float wyz = wy_[cyz & 1u] * wz_[cyz >> 1];
        float wa = wxa * wyz, wb = wxb * wyz;
        const float4 t4 = *reinterpret_cast<const float4*>(tbl + 2u * (ha & ~1u));
        float2 ta, tb;
        if (ha & 1u) { ta.x = t4.z; ta.y = t4.w; tb.x = t4.x; tb.y = t4.y; }
        else         { ta.x = t4.x; ta.y = t4.y; tb.x = t4.z; tb.y = t4.w; }
        f0 += wa * ta.x; f1 += wa * ta.y;
        f0 += wb * tb.x; f1 += wb * tb.y;
      }
    } else {
      #pragma unroll
      for (int cyz = 0; cyz < 4; ++cyz) {
        uint32_t cy = gy + (cyz & 1u);
        uint32_t cz = gz + (cyz >> 1);
        uint32_t hy = (cy * 2654435761u) ^ (cz * 805459861u);
        uint32_t ha = (gx ^ hy) & mask;
        uint32_t hb = ((gx + 1u) ^ hy) & mask;
        float wyz = wy_[cyz & 1u] * wz_[cyz >> 1];
        float wa = wxa * wyz, wb = wxb * wyz;
        const float2 ta = *reinterpret_cast<const float2*>(tbl + 2u * ha);
        const float2 tb = *reinterpret_cast<const float2*>(tbl + 2u * hb);
        f0 += wa * ta.x; f1 += wa * ta.y;
        f0 += wb * tb.x; f1 += wb * tb.y;
      }
    }
    r0[q] = f0; r1[q] = f1;
  }

  evf2 v0; v0.x = r0[0]; v0.y = r1[0];
  __builtin_nontemporal_store(v0, reinterpret_cast<evf2*>(tmp + p0));
  if (p0 + 1 < n) {
    evf2 v1; v1.x = r0[1]; v1.y = r1[1];
    __builtin_nontemporal_store(v1, reinterpret_cast<evf2*>(tmp + p0 + 1));
  }
}

// ---------- dense levels 0..5 -> tmp slots 10..15 ----------
__global__ __launch_bounds__(256) void dense_kernel(
    const float* __restrict__ positions,
    const float* __restrict__ table,
    float2* __restrict__ tmp,           // [16][n] float2, slots 10..15
    ParamsD prm, int n)
{
  int p = blockIdx.x * 256 + threadIdx.x;
  if (p >= n) return;

  float x = (ntload(positions + 3*p+0) + 1.0f) * 0.5f;
  float y = (ntload(positions + 3*p+1) + 1.0f) * 0.5f;
  float z = (ntload(positions + 3*p+2) + 1.0f) * 0.5f;

  #pragma unroll
  for (int l = 0; l < NDENSE; ++l) {
    const float s = prm.scale[l];
    const uint32_t res = prm.res[l];
    const uint32_t ms = prm.msize[l];
    const float* __restrict__ tbl = table + 2u * prm.offset[l];
    const uint32_t res2 = res * res;

    float px = x * s + 0.5f;
    float py = y * s + 0.5f;
    float pz = z * s + 0.5f;
    float fx = floorf(px), fy = floorf(py), fz = floorf(pz);
    float tx = px - fx, ty = py - fy, tz = pz - fz;
    uint32_t gx = (uint32_t)fx, gy = (uint32_t)fy, gz = (uint32_t)fz;

    float wxa = 1.0f - tx, wxb = tx;
    float wy_[2] = {1.0f - ty, ty};
    float wz_[2] = {1.0f - tz, tz};

    float f0 = 0.0f, f1 = 0.0f;
    #pragma unroll
    for (int cyz = 0; cyz < 4; ++cyz) {
      uint32_t cy = gy + (cyz & 1u);
      uint32_t cz = gz + ((cyz >> 1) & 1u);
      uint32_t h = gx + cy * res + cz * res2;   // raw in [0, 2*ms)
      if (h >= ms) h -= ms;
      float wyz = wy_[cyz & 1u] * wz_[(cyz >> 1) & 1u];
      float2 ta, tb;
      if (h + 1u < ms) {
        const float4 t4 = *reinterpret_cast<const float4*>(tbl + 2u * h);
        ta.x = t4.x; ta.y = t4.y; tb.x = t4.z; tb.y = t4.w;
      } else {
        ta = *reinterpret_cast<const float2*>(tbl + 2u * h);
        tb = *reinterpret_cast<const float2*>(tbl);
      }
      float wa = wxa * wyz, wb = wxb * wyz;
      f0 += wa * ta.x; f1 += wa * ta.y;
      f0 += wb * tb.x; f1 += wb * tb.y;
    }
    evf2 v; v.x = f0; v.y = f1;
    __builtin_nontemporal_store(v,
        reinterpret_cast<evf2*>(tmp + (size_t)(NHASH + l) * n + p));
  }
}

// ---------- pack with un-sort: LDS transpose + line-grouped scattered writes ----------
__global__ __launch_bounds__(256) void pack_scatter_kernel(
    const float2* __restrict__ tmp,     // [16][n] float2, sorted space
    const uint32_t* __restrict__ origIdx,
    float* __restrict__ out, int n)
{
  __shared__ float lds[256 * 33];       // pad 33: conflict-free both phases
  int t = threadIdx.x;
  int base = blockIdx.x * 256;
  int p = base + t;

  if (p < n) {
    #pragma unroll
    for (int j = 0; j < NDENSE; ++j) {
      evf2 v = __builtin_nontemporal_load(
          reinterpret_cast<const evf2*>(tmp + (size_t)(NHASH + j) * n + p));
      lds[t*33 + 2*j]     = v.x;
      lds[t*33 + 2*j + 1] = v.y;
    }
    #pragma unroll
    for (int j = 0; j < NHASH; ++j) {
      evf2 v = __builtin_nontemporal_load(
          reinterpret_cast<const evf2*>(tmp + (size_t)j * n + p));
      lds[t*33 + 12 + 2*j]     = v.x;
      lds[t*33 + 12 + 2*j + 1] = v.y;
    }
  }
  __syncthreads();

  if (base + 256 <= n) {
    // each store instr: 256 lanes cover 32 points x 8 float4 -> few distinct
    // lines per wave instead of 64 (each point's 128 B output is one line)
    int qr = t >> 3, r = t & 7;
    #pragma unroll
    for (int k = 0; k < 8; ++k) {
      int q = k * 32 + qr;
      uint32_t oi = origIdx[base + q];
      float4 v = make_float4(lds[q*33 + r*4], lds[q*33 + r*4 + 1],
                             lds[q*33 + r*4 + 2], lds[q*33 + r*4 + 3]);
      reinterpret_cast<float4*>(out + (size_t)oi * 32u)[r] = v;
    }
  } else if (p < n) {                   // partial tail block: per-point writes
    uint32_t oi = origIdx[p];
    float4* o = reinterpret_cast<float4*>(out + (size_t)oi * 32u);
    #pragma unroll
    for (int k = 0; k < 8; ++k)
      o[k] = make_float4(lds[t*33 + 4*k], lds[t*33 + 4*k + 1],
                         lds[t*33 + 4*k + 2], lds[t*33 + 4*k + 3]);
  }
}

// ---------- non-sorted pack (R7 path) ----------
__global__ __launch_bounds__(256) void stream_pack_kernel(
    const float2* __restrict__ tmp, float* __restrict__ out, int n)
{
  int p = blockIdx.x * 256 + threadIdx.x;
  if (p >= n) return;

  evf2 dv[NDENSE];
  #pragma unroll
  for (int j = 0; j < NDENSE; ++j)
    dv[j] = __builtin_nontemporal_load(
        reinterpret_cast<const evf2*>(tmp + (size_t)(NHASH + j) * n + p));
  evf2 hv[NHASH];
  #pragma unroll
  for (int j = 0; j < NHASH; ++j)
    hv[j] = __builtin_nontemporal_load(
        reinterpret_cast<const evf2*>(tmp + (size_t)j * n + p));

  float4* o = reinterpret_cast<float4*>(out + (size_t)p * 32u);
  #pragma unroll
  for (int j = 0; j < 3; ++j)
    o[j] = make_float4(dv[2*j].x, dv[2*j].y, dv[2*j+1].x, dv[2*j+1].y);
  #pragma unroll
  for (int j = 0; j < 5; ++j)
    o[3 + j] = make_float4(hv[2*j].x, hv[2*j].y, hv[2*j+1].x, hv[2*j+1].y);
}

// ---------- last-resort fallback: single fused kernel ----------
__global__ __launch_bounds__(256) void hash_enc_kernel(
    const float* __restrict__ positions,
    const float* __restrict__ table,
    float* __restrict__ out,
    Params prm, int n)
{
  int p = blockIdx.x * 256 + threadIdx.x;
  if (p >= n) return;

  float x = (positions[3*p+0] + 1.0f) * 0.5f;
  float y = (positions[3*p+1] + 1.0f) * 0.5f;
  float z = (positions[3*p+2] + 1.0f) * 0.5f;

  float acc[32];

  #pragma unroll
  for (int l = 0; l < NLV; ++l) {
    const float s = prm.scale[l];
    const uint32_t res = prm.res[l];
    const uint32_t ms = prm.msize[l];
    const uint32_t off = prm.offset[l];

    float px = x * s + 0.5f;
    float py = y * s + 0.5f;
    float pz = z * s + 0.5f;
    float fx = floorf(px), fy = floorf(py), fz = floorf(pz);
    float tx = px - fx, ty = py - fy, tz = pz - fz;
    uint32_t gx = (uint32_t)fx, gy = (uint32_t)fy, gz = (uint32_t)fz;

    float wx[2] = {1.0f - tx, tx};
    float wy[2] = {1.0f - ty, ty};
    float wz[2] = {1.0f - tz, tz};

    float f0 = 0.0f, f1 = 0.0f;
    #pragma unroll
    for (int c = 0; c < 8; ++c) {
      uint32_t cx = gx + (c & 1u);
      uint32_t cy = gy + ((c >> 1) & 1u);
      uint32_t cz = gz + ((c >> 2) & 1u);
      uint32_t h;
      if (l < NDENSE) {
        h = cx + cy * res + cz * res * res;
        if (h >= ms) h -= ms;
      } else {
        h = cx ^ (cy * 2654435761u) ^ (cz * 805459861u);
        h &= (ms - 1u);
      }
      float w = (wx[c & 1u] * wy[(c >> 1) & 1u]) * wz[(c >> 2) & 1u];
      const float2 t = *reinterpret_cast<const float2*>(table + 2u * (h + off));
      f0 += w * t.x;
      f1 += w * t.y;
    }
    acc[2*l]   = f0;
    acc[2*l+1] = f1;
  }

  float4* o = reinterpret_cast<float4*>(out + (size_t)p * 32u);
  #pragma unroll
  for (int k = 0; k < 8; ++k)
    o[k] = make_float4(acc[4*k+0], acc[4*k+1], acc[4*k+2], acc[4*k+3]);
}

extern "C" void kernel_launch(void* const* d_in, const int* in_sizes, int n_in,
                              void* d_out, int out_size, void* d_ws, size_t ws_size,
                              hipStream_t stream) {
  const float* positions = (const float*)d_in[0];
  const float* table     = (const float*)d_in[1];
  float* out             = (float*)d_out;
  int n = in_sizes[0] / 3;

  // Level metadata, exactly mirroring the reference (f64 exp/log; f32 cast
  // for the encode-path scale; level 5 is dense with res=65 due to the
  // B_SCALE^5 = 4.0000007 float quirk).
  Params prm;
  const double lnb = log(1.3195079565048218);
  uint32_t off = 0;
  for (int l = 0; l < NLV; ++l) {
    double sd = 16.0 * exp((double)l * lnb) - 1.0;
    uint32_t res_meta = (uint32_t)ceil(sd) + 1u;
    uint64_t p3 = (uint64_t)res_meta * res_meta * res_meta;
    uint64_t ps = (p3 % 8ull) ? ((p3 + 7ull) / 8ull) * 8ull : p3;
    if (ps > (1ull << 19)) ps = 1ull << 19;
    float sf = (float)sd;
    uint32_t res_enc = (uint32_t)(ceilf(sf) + 1.0f);
    prm.scale[l]  = sf;
    prm.res[l]    = res_enc;
    prm.msize[l]  = (uint32_t)ps;
    prm.offset[l] = off;
    off += (uint32_t)ps;
  }
  ParamsD pd;
  for (int l = 0; l < NDENSE; ++l) {
    pd.scale[l] = prm.scale[l]; pd.res[l] = prm.res[l];
    pd.msize[l] = prm.msize[l]; pd.offset[l] = prm.offset[l];
  }

  dim3 block(256);
  dim3 gfull((n + 255) / 256);
  dim3 ghash((n/2 + 255) / 256);

  // ws layout: [tmp 16*n*8][sortedPos 3*n*4][origIdx n*4][bins][cursor]
  size_t tmp_b  = (size_t)NLV * n * sizeof(float2);
  size_t sp_off = tmp_b;
  size_t oi_off = sp_off + (size_t)3 * n * sizeof(float);
  size_t bn_off = oi_off + (size_t)n * sizeof(uint32_t);
  size_t cu_off = bn_off + (size_t)NBINS * sizeof(uint32_t);
  size_t total  = cu_off + (size_t)NBINS * sizeof(uint32_t);
  size_t ws16   = tmp_b;

  char* wsb = (char*)d_ws;

  if (ws_size >= total && (n % 2) == 0) {
    // ---- sorted path ----
    float2*   tmp       = (float2*)wsb;
    float*    sortedPos = (float*)(wsb + sp_off);
    uint32_t* origIdx   = (uint32_t*)(wsb + oi_off);
    uint32_t* bins      = (uint32_t*)(wsb + bn_off);
    uint32_t* cursor    = (uint32_t*)(wsb + cu_off);

    hipLaunchKernelGGL(zero_bins_kernel, dim3((NBINS + 255) / 256), block, 0, stream, bins);
    hipLaunchKernelGGL(hist_kernel, gfull, block, 0, stream, positions, bins, n);
    hipLaunchKernelGGL(scan_kernel, dim3(1), dim3(1024), 0, stream, bins, cursor);
    hipLaunchKernelGGL(scatter_kernel, gfull, block, 0, stream,
                       positions, cursor, sortedPos, origIdx, n);

    for (int l = NDENSE; l < NLV; ++l) {
      hipLaunchKernelGGL(hash_level_kernel, ghash, block, 0, stream,
                         sortedPos, table + 2u * prm.offset[l],
                         tmp + (size_t)(l - NDENSE) * n,
                         prm.scale[l], prm.msize[l] - 1u, n);
    }
    hipLaunchKernelGGL(dense_kernel, gfull, block, 0, stream,
                       sortedPos, table, tmp, pd, n);
    hipLaunchKernelGGL(pack_scatter_kernel, gfull, block, 0, stream,
                       tmp, origIdx, out, n);
  } else if (ws_size >= ws16 && (n % 2) == 0) {
    // ---- R7 three-stage fallback (no sort) ----
    float2* tmp = (float2*)d_ws;
    for (int l = NDENSE; l < NLV; ++l) {
      hipLaunchKernelGGL(hash_level_kernel, ghash, block, 0, stream,
                         positions, table + 2u * prm.offset[l],
                         tmp + (size_t)(l - NDENSE) * n,
                         prm.scale[l], prm.msize[l] - 1u, n);
    }
    hipLaunchKernelGGL(dense_kernel, gfull, block, 0, stream,
                       positions, table, tmp, pd, n);
    hipLaunchKernelGGL(stream_pack_kernel, gfull, block, 0, stream,
                       tmp, out, n);
  } else {
    hipLaunchKernelGGL(hash_enc_kernel, gfull, block, 0, stream,
                       positions, table, out, prm, n);
  }
}

// Round 10
// 436.198 us; speedup vs baseline: 1.2777x; 1.0286x over previous
//
#include <hip/hip_runtime.h>
#include <math.h>
#include <stdint.h>

#define NLV 16
#define NDENSE 6
#define NHASH 10
#define SORT_RES 32
#define NBINS (SORT_RES * SORT_RES * SORT_RES)   // 32768

typedef float evf2 __attribute__((ext_vector_type(2)));
typedef unsigned int evu4 __attribute__((ext_vector_type(4)));

struct Params {          // all 16 levels (fallback kernel)
  float scale[NLV];
  uint32_t res[NLV];
  uint32_t msize[NLV];
  uint32_t offset[NLV];
};

struct ParamsD {         // dense levels 0..5
  float scale[NDENSE];
  uint32_t res[NDENSE];
  uint32_t msize[NDENSE];
  uint32_t offset[NDENSE];
};

__device__ __forceinline__ float ntload(const float* p) {
  return __builtin_nontemporal_load(p);
}

__device__ __forceinline__ uint32_t cell_key(float xr, float yr, float zr) {
  float x01 = (xr + 1.0f) * 0.5f;
  float y01 = (yr + 1.0f) * 0.5f;
  float z01 = (zr + 1.0f) * 0.5f;
  int cx = (int)(x01 * (float)SORT_RES);
  int cy = (int)(y01 * (float)SORT_RES);
  int cz = (int)(z01 * (float)SORT_RES);
  cx = cx < 0 ? 0 : (cx > SORT_RES-1 ? SORT_RES-1 : cx);
  cy = cy < 0 ? 0 : (cy > SORT_RES-1 ? SORT_RES-1 : cy);
  cz = cz < 0 ? 0 : (cz > SORT_RES-1 ? SORT_RES-1 : cz);
  return (uint32_t)(cx | (cy << 5) | (cz << 10));
}

// ---------------- sort machinery ----------------
__global__ __launch_bounds__(256) void zero_bins_kernel(uint32_t* bins) {
  int i = blockIdx.x * 256 + threadIdx.x;
  if (i < NBINS) bins[i] = 0u;
}

// 4 pts/thread, batched float4 reads
__global__ __launch_bounds__(256) void hist_kernel(
    const float* __restrict__ positions, uint32_t* __restrict__ bins, int n) {
  int t = blockIdx.x * 256 + threadIdx.x;
  int p0 = t * 4;
  if (p0 >= n) return;
  const float4 A = *reinterpret_cast<const float4*>(positions + 3*p0);
  const float4 B = *reinterpret_cast<const float4*>(positions + 3*p0 + 4);
  const float4 C = *reinterpret_cast<const float4*>(positions + 3*p0 + 8);
  atomicAdd(&bins[cell_key(A.x, A.y, A.z)], 1u);
  atomicAdd(&bins[cell_key(A.w, B.x, B.y)], 1u);
  atomicAdd(&bins[cell_key(B.z, B.w, C.x)], 1u);
  atomicAdd(&bins[cell_key(C.y, C.z, C.w)], 1u);
}

// single block, 1024 threads, 32 bins each: exclusive scan -> cursor
__global__ __launch_bounds__(1024) void scan_kernel(
    const uint32_t* __restrict__ bins, uint32_t* __restrict__ cursor) {
  __shared__ uint32_t lds[1024];
  int t = threadIdx.x;
  uint32_t local[32];
  uint32_t s = 0;
  #pragma unroll
  for (int j = 0; j < 32; ++j) { local[j] = bins[t*32 + j]; s += local[j]; }
  lds[t] = s;
  __syncthreads();
  for (int off = 1; off < 1024; off <<= 1) {
    uint32_t v = (t >= off) ? lds[t - off] : 0u;
    __syncthreads();
    lds[t] += v;
    __syncthreads();
  }
  uint32_t run = lds[t] - s;
  #pragma unroll
  for (int j = 0; j < 32; ++j) { cursor[t*32 + j] = run; run += local[j]; }
}

// 4 pts/thread; ONE uint4 store per point: (x,y,z,origIdx)
__global__ __launch_bounds__(256) void scatter_kernel(
    const float* __restrict__ positions, uint32_t* __restrict__ cursor,
    evu4* __restrict__ spi, int n) {
  int t = blockIdx.x * 256 + threadIdx.x;
  int p0 = t * 4;
  if (p0 >= n) return;
  const float4 A = *reinterpret_cast<const float4*>(positions + 3*p0);
  const float4 B = *reinterpret_cast<const float4*>(positions + 3*p0 + 4);
  const float4 C = *reinterpret_cast<const float4*>(positions + 3*p0 + 8);
  float xs[4] = {A.x, A.w, B.z, C.y};
  float ys[4] = {A.y, B.x, B.w, C.z};
  float zs[4] = {A.z, B.y, C.x, C.w};
  #pragma unroll
  for (int q = 0; q < 4; ++q) {
    uint32_t k = cell_key(xs[q], ys[q], zs[q]);
    uint32_t dst = atomicAdd(&cursor[k], 1u);
    evu4 v;
    v.x = __float_as_uint(xs[q]);
    v.y = __float_as_uint(ys[q]);
    v.z = __float_as_uint(zs[q]);
    v.w = (uint32_t)(p0 + q);
    spi[dst] = v;
  }
}

// ---------- per-hashed-level pass (sorted space): tmp[p] = feat2, 2 pts/thread ----------
__global__ __launch_bounds__(256) void hash_level_kernel(
    const evu4* __restrict__ spi,
    const float* __restrict__ tbl,
    float2* __restrict__ tmp,
    float scale, uint32_t mask, int n)
{
  int t = blockIdx.x * 256 + threadIdx.x;
  int p0 = t * 2;
  if (p0 >= n) return;

  evu4 a = __builtin_nontemporal_load(spi + p0);
  evu4 b = (p0 + 1 < n) ? __builtin_nontemporal_load(spi + p0 + 1) : a;
  float xx[2] = {__uint_as_float(a.x), __uint_as_float(b.x)};
  float yy[2] = {__uint_as_float(a.y), __uint_as_float(b.y)};
  float zz[2] = {__uint_as_float(a.z), __uint_as_float(b.z)};

  float r0[2], r1[2];
  #pragma unroll
  for (int q = 0; q < 2; ++q) {
    float x = (xx[q] + 1.0f) * 0.5f;
    float y = (yy[q] + 1.0f) * 0.5f;
    float z = (zz[q] + 1.0f) * 0.5f;

    float px = x * scale + 0.5f;
    float py = y * scale + 0.5f;
    float pz = z * scale + 0.5f;
    float fx = floorf(px), fy = floorf(py), fz = floorf(pz);
    float tx = px - fx, ty = py - fy, tz = pz - fz;
    uint32_t gx = (uint32_t)fx, gy = (uint32_t)fy, gz = (uint32_t)fz;

    float wxa = 1.0f - tx, wxb = tx;
    float wy_[2] = {1.0f - ty, ty};
    float wz_[2] = {1.0f - tz, tz};

    float f0 = 0.0f, f1 = 0.0f;

    if ((gx & 1u) == 0u) {
      #pragma unroll
      for (int cyz = 0; cyz < 4; ++cyz) {
        uint32_t cy = gy + (cyz & 1u);
        uint32_t cz = gz + (cyz >> 1);
        uint32_t hy = (cy * 2654435761u) ^ (cz * 805459861u);
        uint32_t ha = (gx ^ hy) & mask;
        float wyz = wy_[cyz & 1u] * wz_[cyz >> 1];
        float wa = wxa * wyz, wb = wxb * wyz;
        const float4 t4 = *reinterpret_cast<const float4*>(tbl + 2u * (ha & ~1u));
        float2 ta, tb;
        if (ha & 1u) { ta.x = t4.z; ta.y = t4.w; tb.x = t4.x; tb.y = t4.y; }
        else         { ta.x = t4.x; ta.y = t4.y; tb.x = t4.z; tb.y = t4.w; }
        f0 += wa * ta.x; f1 += wa * ta.y;
        f0 += wb * tb.x; f1 += wb * tb.y;
      }
    } else {
      #pragma unroll
      for (int cyz = 0; cyz < 4; ++cyz) {
        uint32_t cy = gy + (cyz & 1u);
        uint32_t cz = gz + (cyz >> 1);
        uint32_t hy = (cy * 2654435761u) ^ (cz * 805459861u);
        uint32_t ha = (gx ^ hy) & mask;
        uint32_t hb = ((gx + 1u) ^ hy) & mask;
        float wyz = wy_[cyz & 1u] * wz_[cyz >> 1];
        float wa = wxa * wyz, wb = wxb * wyz;
        const float2 ta = *reinterpret_cast<const float2*>(tbl + 2u * ha);
        const float2 tb = *reinterpret_cast<const float2*>(tbl + 2u * hb);
        f0 += wa * ta.x; f1 += wa * ta.y;
        f0 += wb * tb.x; f1 += wb * tb.y;
      }
    }
    r0[q] = f0; r1[q] = f1;
  }

  evf2 v0; v0.x = r0[0]; v0.y = r1[0];
  __builtin_nontemporal_store(v0, reinterpret_cast<evf2*>(tmp + p0));
  if (p0 + 1 < n) {
    evf2 v1; v1.x = r0[1]; v1.y = r1[1];
    __builtin_nontemporal_store(v1, reinterpret_cast<evf2*>(tmp + p0 + 1));
  }
}

// ---------- fused: dense gathers (sorted, L1-hot) + read hash tmps + un-sort pack ----------
__global__ __launch_bounds__(256) void dense_pack2_kernel(
    const evu4* __restrict__ spi,       // sorted (x,y,z,origIdx)
    const float* __restrict__ table,
    const float2* __restrict__ tmp,     // [NHASH][n] float2, sorted space
    float* __restrict__ out,
    ParamsD prm, int n)
{
  __shared__ float lds[256 * 33];       // 32 floats/point + pad
  __shared__ uint32_t lds_oi[256];
  int t = threadIdx.x;
  int base = blockIdx.x * 256;
  int p = base + t;

  if (p < n) {
    evu4 a = __builtin_nontemporal_load(spi + p);
    float x = (__uint_as_float(a.x) + 1.0f) * 0.5f;
    float y = (__uint_as_float(a.y) + 1.0f) * 0.5f;
    float z = (__uint_as_float(a.z) + 1.0f) * 0.5f;
    lds_oi[t] = a.w;

    #pragma unroll
    for (int l = 0; l < NDENSE; ++l) {
      const float s = prm.scale[l];
      const uint32_t res = prm.res[l];
      const uint32_t ms = prm.msize[l];
      const float* __restrict__ tbl = table + 2u * prm.offset[l];
      const uint32_t res2 = res * res;

      float px = x * s + 0.5f;
      float py = y * s + 0.5f;
      float pz = z * s + 0.5f;
      float fx = floorf(px), fy = floorf(py), fz = floorf(pz);
      float tx = px - fx, ty = py - fy, tz = pz - fz;
      uint32_t gx = (uint32_t)fx, gy = (uint32_t)fy, gz = (uint32_t)fz;

      float wxa = 1.0f - tx, wxb = tx;
      float wy_[2] = {1.0f - ty, ty};
      float wz_[2] = {1.0f - tz, tz};

      float f0 = 0.0f, f1 = 0.0f;
      #pragma unroll
      for (int cyz = 0; cyz < 4; ++cyz) {
        uint32_t cy = gy + (cyz & 1u);
        uint32_t cz = gz + ((cyz >> 1) & 1u);
        uint32_t h = gx + cy * res + cz * res2;   // raw in [0, 2*ms)
        if (h >= ms) h -= ms;
        float wyz = wy_[cyz & 1u] * wz_[(cyz >> 1) & 1u];
        float2 ta, tb;
        if (h + 1u < ms) {
          const float4 t4 = *reinterpret_cast<const float4*>(tbl + 2u * h);
          ta.x = t4.x; ta.y = t4.y; tb.x = t4.z; tb.y = t4.w;
        } else {                                  // h == ms-1: b wraps to 0
          ta = *reinterpret_cast<const float2*>(tbl + 2u * h);
          tb = *reinterpret_cast<const float2*>(tbl);
        }
        float wa = wxa * wyz, wb = wxb * wyz;
        f0 += wa * ta.x; f1 += wa * ta.y;
        f0 += wb * tb.x; f1 += wb * tb.y;
      }
      lds[t*33 + 2*l]     = f0;
      lds[t*33 + 2*l + 1] = f1;
    }

    #pragma unroll
    for (int j = 0; j < NHASH; ++j) {
      evf2 v = __builtin_nontemporal_load(
          reinterpret_cast<const evf2*>(tmp + (size_t)j * n + p));
      lds[t*33 + 12 + 2*j]     = v.x;
      lds[t*33 + 12 + 2*j + 1] = v.y;
    }
  }
  __syncthreads();

  if (base + 256 <= n) {
    // line-grouped un-sort: 8 lanes cover one point's full 128 B output line
    int qr = t >> 3, r = t & 7;
    #pragma unroll
    for (int k = 0; k < 8; ++k) {
      int q = k * 32 + qr;
      uint32_t oi = lds_oi[q];
      float4 v = make_float4(lds[q*33 + r*4], lds[q*33 + r*4 + 1],
                             lds[q*33 + r*4 + 2], lds[q*33 + r*4 + 3]);
      reinterpret_cast<float4*>(out + (size_t)oi * 32u)[r] = v;
    }
  } else if (p < n) {                   // partial tail block
    uint32_t oi = lds_oi[t];
    float4* o = reinterpret_cast<float4*>(out + (size_t)oi * 32u);
    #pragma unroll
    for (int k = 0; k < 8; ++k)
      o[k] = make_float4(lds[t*33 + 4*k], lds[t*33 + 4*k + 1],
                         lds[t*33 + 4*k + 2], lds[t*33 + 4*k + 3]);
  }
}

// ================= unsorted fallback path (R7) =================
__global__ __launch_bounds__(256) void hash_level_unsorted_kernel(
    const float* __restrict__ positions,
    const float* __restrict__ tbl,
    float2* __restrict__ tmp,
    float scale, uint32_t mask, int n)
{
  int t = blockIdx.x * 256 + threadIdx.x;
  int p0 = t * 2;
  if (p0 >= n) return;

  float xx[2], yy[2], zz[2];
  {
    evf2 a = __builtin_nontemporal_load(reinterpret_cast<const evf2*>(positions + 3*p0));
    evf2 b = __builtin_nontemporal_load(reinterpret_cast<const evf2*>(positions + 3*p0 + 2));
    evf2 c = __builtin_nontemporal_load(reinterpret_cast<const evf2*>(positions + 3*p0 + 4));
    xx[0] = a.x; yy[0] = a.y; zz[0] = b.x;
    xx[1] = b.y; yy[1] = c.x; zz[1] = c.y;
  }

  float r0[2], r1[2];
  #pragma unroll
  for (int q = 0; q < 2; ++q) {
    float x = (xx[q] + 1.0f) * 0.5f;
    float y = (yy[q] + 1.0f) * 0.5f;
    float z = (zz[q] + 1.0f) * 0.5f;
    float px = x * scale + 0.5f;
    float py = y * scale + 0.5f;
    float pz = z * scale + 0.5f;
    float fx = floorf(px), fy = floorf(py), fz = floorf(pz);
    float tx = px - fx, ty = py - fy, tz = pz - fz;
    uint32_t gx = (uint32_t)fx, gy = (uint32_t)fy, gz = (uint32_t)fz;
    float wxa = 1.0f - tx, wxb = tx;
    float wy_[2] = {1.0f - ty, ty};
    float wz_[2] = {1.0f - tz, tz};
    float f0 = 0.0f, f1 = 0.0f;
    #pragma unroll
    for (int cyz = 0; cyz < 4; ++cyz) {
      uint32_t cy = gy + (cyz & 1u);
      uint32_t cz = gz + (cyz >> 1);
      uint32_t hy = (cy * 2654435761u) ^ (cz * 805459861u);
      uint32_t ha = (gx ^ hy) & mask;
      uint32_t hb = ((gx + 1u) ^ hy) & mask;
      float wyz = wy_[cyz & 1u] * wz_[cyz >> 1];
      float wa = wxa * wyz, wb = wxb * wyz;
      const float2 ta = *reinterpret_cast<const float2*>(tbl + 2u * ha);
      const float2 tb = *reinterpret_cast<const float2*>(tbl + 2u * hb);
      f0 += wa * ta.x; f1 += wa * ta.y;
      f0 += wb * tb.x; f1 += wb * tb.y;
    }
    r0[q] = f0; r1[q] = f1;
  }
  evf2 v0; v0.x = r0[0]; v0.y = r1[0];
  __builtin_nontemporal_store(v0, reinterpret_cast<evf2*>(tmp + p0));
  if (p0 + 1 < n) {
    evf2 v1; v1.x = r0[1]; v1.y = r1[1];
    __builtin_nontemporal_store(v1, reinterpret_cast<evf2*>(tmp + p0 + 1));
  }
}

__global__ __launch_bounds__(256) void dense_unsorted_kernel(
    const float* __restrict__ positions,
    const float* __restrict__ table,
    float2* __restrict__ tmp,           // [16][n] float2, slots 10..15
    ParamsD prm, int n)
{
  int p = blockIdx.x * 256 + threadIdx.x;
  if (p >= n) return;

  float x = (ntload(positions + 3*p+0) + 1.0f) * 0.5f;
  float y = (ntload(positions + 3*p+1) + 1.0f) * 0.5f;
  float z = (ntload(positions + 3*p+2) + 1.0f) * 0.5f;

  #pragma unroll
  for (int l = 0; l < NDENSE; ++l) {
    const float s = prm.scale[l];
    const uint32_t res = prm.res[l];
    const uint32_t ms = prm.msize[l];
    const float* __restrict__ tbl = table + 2u * prm.offset[l];
    const uint32_t res2 = res * res;
    float px = x * s + 0.5f;
    float py = y * s + 0.5f;
    float pz = z * s + 0.5f;
    float fx = floorf(px), fy = floorf(py), fz = floorf(pz);
    float tx = px - fx, ty = py - fy, tz = pz - fz;
    uint32_t gx = (uint32_t)fx, gy = (uint32_t)fy, gz = (uint32_t)fz;
    float wxa = 1.0f - tx, wxb = tx;
    float wy_[2] = {1.0f - ty, ty};
    float wz_[2] = {1.0f - tz, tz};
    float f0 = 0.0f, f1 = 0.0f;
    #pragma unroll
    for (int cyz = 0; cyz < 4; ++cyz) {
      uint32_t cy = gy + (cyz & 1u);
      uint32_t cz = gz + ((cyz >> 1) & 1u);
      uint32_t h = gx + cy * res + cz * res2;
      if (h >= ms) h -= ms;
      float wyz = wy_[cyz & 1u] * wz_[(cyz >> 1) & 1u];
      float2 ta, tb;
      if (h + 1u < ms) {
        const float4 t4 = *reinterpret_cast<const float4*>(tbl + 2u * h);
        ta.x = t4.x; ta.y = t4.y; tb.x = t4.z; tb.y = t4.w;
      } else {
        ta = *reinterpret_cast<const float2*>(tbl + 2u * h);
        tb = *reinterpret_cast<const float2*>(tbl);
      }
      float wa = wxa * wyz, wb = wxb * wyz;
      f0 += wa * ta.x; f1 += wa * ta.y;
      f0 += wb * tb.x; f1 += wb * tb.y;
    }
    evf2 v; v.x = f0; v.y = f1;
    __builtin_nontemporal_store(v,
        reinterpret_cast<evf2*>(tmp + (size_t)(NHASH + l) * n + p));
  }
}

__global__ __launch_bounds__(256) void stream_pack_kernel(
    const float2* __restrict__ tmp, float* __restrict__ out, int n)
{
  int p = blockIdx.x * 256 + threadIdx.x;
  if (p >= n) return;
  evf2 dv[NDENSE];
  #pragma unroll
  for (int j = 0; j < NDENSE; ++j)
    dv[j] = __builtin_nontemporal_load(
        reinterpret_cast<const evf2*>(tmp + (size_t)(NHASH + j) * n + p));
  evf2 hv[NHASH];
  #pragma unroll
  for (int j = 0; j < NHASH; ++j)
    hv[j] = __builtin_nontemporal_load(
        reinterpret_cast<const evf2*>(tmp + (size_t)j * n + p));
  float4* o = reinterpret_cast<float4*>(out + (size_t)p * 32u);
  #pragma unroll
  for (int j = 0; j < 3; ++j)
    o[j] = make_float4(dv[2*j].x, dv[2*j].y, dv[2*j+1].x, dv[2*j+1].y);
  #pragma unroll
  for (int j = 0; j < 5; ++j)
    o[3 + j] = make_float4(hv[2*j].x, hv[2*j].y, hv[2*j+1].x, hv[2*j+1].y);
}

// ---------- last-resort fallback: single fused kernel ----------
__global__ __launch_bounds__(256) void hash_enc_kernel(
    const float* __restrict__ positions,
    const float* __restrict__ table,
    float* __restrict__ out,
    Params prm, int n)
{
  int p = blockIdx.x * 256 + threadIdx.x;
  if (p >= n) return;

  float x = (positions[3*p+0] + 1.0f) * 0.5f;
  float y = (positions[3*p+1] + 1.0f) * 0.5f;
  float z = (positions[3*p+2] + 1.0f) * 0.5f;

  float acc[32];

  #pragma unroll
  for (int l = 0; l < NLV; ++l) {
    const float s = prm.scale[l];
    const uint32_t res = prm.res[l];
    const uint32_t ms = prm.msize[l];
    const uint32_t off = prm.offset[l];
    float px = x * s + 0.5f;
    float py = y * s + 0.5f;
    float pz = z * s + 0.5f;
    float fx = floorf(px), fy = floorf(py), fz = floorf(pz);
    float tx = px - fx, ty = py - fy, tz = pz - fz;
    uint32_t gx = (uint32_t)fx, gy = (uint32_t)fy, gz = (uint32_t)fz;
    float wx[2] = {1.0f - tx, tx};
    float wy[2] = {1.0f - ty, ty};
    float wz[2] = {1.0f - tz, tz};
    float f0 = 0.0f, f1 = 0.0f;
    #pragma unroll
    for (int c = 0; c < 8; ++c) {
      uint32_t cx = gx + (c & 1u);
      uint32_t cy = gy + ((c >> 1) & 1u);
      uint32_t cz = gz + ((c >> 2) & 1u);
      uint32_t h;
      if (l < NDENSE) {
        h = cx + cy * res + cz * res * res;
        if (h >= ms) h -= ms;
      } else {
        h = cx ^ (cy * 2654435761u) ^ (cz * 805459861u);
        h &= (ms - 1u);
      }
      float w = (wx[c & 1u] * wy[(c >> 1) & 1u]) * wz[(c >> 2) & 1u];
      const float2 t = *reinterpret_cast<const float2*>(table + 2u * (h + off));
      f0 += w * t.x;
      f1 += w * t.y;
    }
    acc[2*l]   = f0;
    acc[2*l+1] = f1;
  }

  float4* o = reinterpret_cast<float4*>(out + (size_t)p * 32u);
  #pragma unroll
  for (int k = 0; k < 8; ++k)
    o[k] = make_float4(acc[4*k+0], acc[4*k+1], acc[4*k+2], acc[4*k+3]);
}

extern "C" void kernel_launch(void* const* d_in, const int* in_sizes, int n_in,
                              void* d_out, int out_size, void* d_ws, size_t ws_size,
                              hipStream_t stream) {
  const float* positions = (const float*)d_in[0];
  const float* table     = (const float*)d_in[1];
  float* out             = (float*)d_out;
  int n = in_sizes[0] / 3;

  // Level metadata, exactly mirroring the reference (f64 exp/log; f32 cast
  // for the encode-path scale; level 5 is dense with res=65 due to the
  // B_SCALE^5 = 4.0000007 float quirk).
  Params prm;
  const double lnb = log(1.3195079565048218);
  uint32_t off = 0;
  for (int l = 0; l < NLV; ++l) {
    double sd = 16.0 * exp((double)l * lnb) - 1.0;
    uint32_t res_meta = (uint32_t)ceil(sd) + 1u;
    uint64_t p3 = (uint64_t)res_meta * res_meta * res_meta;
    uint64_t ps = (p3 % 8ull) ? ((p3 + 7ull) / 8ull) * 8ull : p3;
    if (ps > (1ull << 19)) ps = 1ull << 19;
    float sf = (float)sd;
    uint32_t res_enc = (uint32_t)(ceilf(sf) + 1.0f);
    prm.scale[l]  = sf;
    prm.res[l]    = res_enc;
    prm.msize[l]  = (uint32_t)ps;
    prm.offset[l] = off;
    off += (uint32_t)ps;
  }
  ParamsD pd;
  for (int l = 0; l < NDENSE; ++l) {
    pd.scale[l] = prm.scale[l]; pd.res[l] = prm.res[l];
    pd.msize[l] = prm.msize[l]; pd.offset[l] = prm.offset[l];
  }

  dim3 block(256);
  dim3 gfull((n + 255) / 256);
  dim3 ghash((n/2 + 255) / 256);
  dim3 gquad((n/4 + 255) / 256);

  // sorted-path ws layout: [tmp 10*n*8][spi n*16][bins][cursor]
  size_t tmp_b  = (size_t)NHASH * n * sizeof(float2);
  size_t sp_off = tmp_b;
  size_t bn_off = sp_off + (size_t)n * sizeof(evu4);
  size_t cu_off = bn_off + (size_t)NBINS * sizeof(uint32_t);
  size_t total  = cu_off + (size_t)NBINS * sizeof(uint32_t);
  size_t ws16   = (size_t)NLV * n * sizeof(float2);  // unsorted fallback needs

  char* wsb = (char*)d_ws;

  if (ws_size >= total && (n % 4) == 0) {
    // ---- sorted path ----
    float2*   tmp    = (float2*)wsb;
    evu4*     spi    = (evu4*)(wsb + sp_off);
    uint32_t* bins   = (uint32_t*)(wsb + bn_off);
    uint32_t* cursor = (uint32_t*)(wsb + cu_off);

    hipLaunchKernelGGL(zero_bins_kernel, dim3((NBINS + 255) / 256), block, 0, stream, bins);
    hipLaunchKernelGGL(hist_kernel, gquad, block, 0, stream, positions, bins, n);
    hipLaunchKernelGGL(scan_kernel, dim3(1), dim3(1024), 0, stream, bins, cursor);
    hipLaunchKernelGGL(scatter_kernel, gquad, block, 0, stream,
                       positions, cursor, spi, n);

    for (int l = NDENSE; l < NLV; ++l) {
      hipLaunchKernelGGL(hash_level_kernel, ghash, block, 0, stream,
                         spi, table + 2u * prm.offset[l],
                         tmp + (size_t)(l - NDENSE) * n,
                         prm.scale[l], prm.msize[l] - 1u, n);
    }
    hipLaunchKernelGGL(dense_pack2_kernel, gfull, block, 0, stream,
                       spi, table, tmp, out, pd, n);
  } else if (ws_size >= ws16 && (n % 2) == 0) {
    // ---- unsorted three-stage fallback ----
    float2* tmp = (float2*)d_ws;
    for (int l = NDENSE; l < NLV; ++l) {
      hipLaunchKernelGGL(hash_level_unsorted_kernel, ghash, block, 0, stream,
                         positions, table + 2u * prm.offset[l],
                         tmp + (size_t)(l - NDENSE) * n,
                         prm.scale[l], prm.msize[l] - 1u, n);
    }
    hipLaunchKernelGGL(dense_unsorted_kernel, gfull, block, 0, stream,
                       positions, table, tmp, pd, n);
    hipLaunchKernelGGL(stream_pack_kernel, gfull, block, 0, stream,
                       tmp, out, n);
  } else {
    hipLaunchKernelGGL(hash_enc_kernel, gfull, block, 0, stream,
                       positions, table, out, prm, n);
  }
}